// Round 2
// baseline (3373.773 us; speedup 1.0000x reference)
//
#include <hip/hip_runtime.h>
#include <hip/hip_bf16.h>
#include <math.h>

#define S_LEN 2048
#define H_DIM 2048
#define NH 16
#define Q_LORA 1536
#define KV_LORA 512
#define D_NOPE 128
#define D_ROPE 64
#define D_V 128
#define D_QK 192

// C[M,N] = A[M,K] (row-major fp32, leading dim lda) * B[K,N] (fp32 row-major)
// 64x64 tile, BK=16, 256 threads, 4x4 per thread, fp32 accumulate.
__global__ __launch_bounds__(256) void gemm_kernel(
    const float* __restrict__ A, int lda,
    const float* __restrict__ B,
    float* __restrict__ C, int M, int N, int K)
{
    __shared__ float As[16][65];  // [k][m], padded
    __shared__ float Bs[16][68];  // [k][n], padded
    const int tx = threadIdx.x, ty = threadIdx.y;
    const int tid = ty * 16 + tx;
    const int m0 = blockIdx.y * 64, n0 = blockIdx.x * 64;
    float acc[4][4] = {};

    for (int k0 = 0; k0 < K; k0 += 16) {
        // A tile: 64 rows x 16 k
        #pragma unroll
        for (int i = 0; i < 4; ++i) {
            int idx = tid + i * 256;       // 0..1023
            int r = idx >> 4;              // m 0..63
            int c = idx & 15;              // k 0..15
            As[c][r] = A[(size_t)(m0 + r) * lda + k0 + c];
        }
        // B tile: 16 k x 64 n
        #pragma unroll
        for (int i = 0; i < 4; ++i) {
            int idx = tid + i * 256;
            int r = idx >> 6;              // k 0..15
            int c = idx & 63;              // n 0..63
            Bs[r][c] = B[(size_t)(k0 + r) * N + n0 + c];
        }
        __syncthreads();
        #pragma unroll
        for (int kk = 0; kk < 16; ++kk) {
            float a[4], b[4];
            #pragma unroll
            for (int i = 0; i < 4; ++i) a[i] = As[kk][ty * 4 + i];
            #pragma unroll
            for (int j = 0; j < 4; ++j) b[j] = Bs[kk][tx * 4 + j];
            #pragma unroll
            for (int i = 0; i < 4; ++i)
                #pragma unroll
                for (int j = 0; j < 4; ++j)
                    acc[i][j] += a[i] * b[j];
        }
        __syncthreads();
    }
    #pragma unroll
    for (int i = 0; i < 4; ++i)
        #pragma unroll
        for (int j = 0; j < 4; ++j)
            C[(size_t)(m0 + ty * 4 + i) * N + n0 + tx * 4 + j] = acc[i][j];
}

// In-place RMSNorm of X[row][0..K) with row stride rowStride; weight w (fp32).
__global__ __launch_bounds__(256) void rmsnorm_kernel(
    float* __restrict__ X, int rowStride, int K,
    const float* __restrict__ w)
{
    __shared__ float red[4];
    float* x = X + (size_t)blockIdx.x * rowStride;
    float ss = 0.f;
    for (int i = threadIdx.x; i < K; i += 256) { float v = x[i]; ss += v * v; }
    #pragma unroll
    for (int off = 32; off > 0; off >>= 1) ss += __shfl_down(ss, off);
    int lane = threadIdx.x & 63, wid = threadIdx.x >> 6;
    if (lane == 0) red[wid] = ss;
    __syncthreads();
    float tot = red[0] + red[1] + red[2] + red[3];
    float rs = rsqrtf(tot / (float)K + 1e-6f);
    for (int i = threadIdx.x; i < K; i += 256)
        x[i] = x[i] * rs * w[i];
}

// RoPE in place: rows s in [0,S), heads hh in [0,nHeads), pair index i in [0,32).
__global__ void rope_kernel(float* __restrict__ X, int rowStride, int headStride,
                            int nHeads, int dimOffset)
{
    int idx = blockIdx.x * 256 + threadIdx.x;
    int total = S_LEN * nHeads * 32;
    if (idx >= total) return;
    int i = idx & 31;
    int sh = idx >> 5;
    int hh = sh % nHeads;
    int s = sh / nHeads;
    float inv = powf(10000.0f, -(2.0f * i) / 64.0f);
    float ang = (float)s * inv;
    float c = cosf(ang), sn = sinf(ang);
    float* p = X + (size_t)s * rowStride + hh * headStride + dimOffset;
    float x1 = p[i], x2 = p[i + 32];
    p[i]      = x1 * c - x2 * sn;
    p[i + 32] = x2 * c + x1 * sn;
}

// Flash attention: block = (16,16); one block handles head h, 16 query rows.
// qbuf: [S][3072] (per head 192: 128 nope + 64 roped pe)
// kvbuf: [S][4096] (per head 256: 128 k_nope + 128 v)
// ckv:   [S][576]  (cols 512..576 = roped k_pe, shared across heads)
__global__ __launch_bounds__(256) void attn_kernel(
    const float* __restrict__ qbuf, const float* __restrict__ kvbuf,
    const float* __restrict__ ckv, float* __restrict__ outbuf)
{
    __shared__ float Qs[16][196];
    __shared__ float Ks[16][196];
    __shared__ float Vs[16][132];
    const int h = blockIdx.y;
    const int q0 = blockIdx.x * 16;
    const int tx = threadIdx.x, ty = threadIdx.y;
    const int tid = ty * 16 + tx;
    const float scale = 0.07216878364870322f;  // 192^-0.5

    for (int idx = tid; idx < 16 * 192; idx += 256) {
        int r = idx / 192, c = idx % 192;
        Qs[r][c] = qbuf[(size_t)(q0 + r) * 3072 + h * 192 + c];
    }

    float o[8] = {};
    float m_row = -1e30f, l_row = 0.f;

    for (int k0 = 0; k0 <= q0; k0 += 16) {
        __syncthreads();
        for (int idx = tid; idx < 16 * 192; idx += 256) {
            int r = idx / 192, c = idx % 192;
            float v;
            if (c < 128) v = kvbuf[(size_t)(k0 + r) * 4096 + h * 256 + c];
            else         v = ckv[(size_t)(k0 + r) * 576 + 512 + (c - 128)];
            Ks[r][c] = v;
        }
        for (int idx = tid; idx < 16 * 128; idx += 256) {
            int r = idx >> 7, c = idx & 127;
            Vs[r][c] = kvbuf[(size_t)(k0 + r) * 4096 + h * 256 + 128 + c];
        }
        __syncthreads();

        float s = 0.f;
        #pragma unroll 8
        for (int d = 0; d < 192; ++d) s += Qs[ty][d] * Ks[tx][d];
        s *= scale;
        if (k0 + tx > q0 + ty) s = -1e30f;

        float sm = s;
        sm = fmaxf(sm, __shfl_xor(sm, 1, 16));
        sm = fmaxf(sm, __shfl_xor(sm, 2, 16));
        sm = fmaxf(sm, __shfl_xor(sm, 4, 16));
        sm = fmaxf(sm, __shfl_xor(sm, 8, 16));
        float m_new = fmaxf(m_row, sm);
        float p = expf(s - m_new);
        float psum = p;
        psum += __shfl_xor(psum, 1, 16);
        psum += __shfl_xor(psum, 2, 16);
        psum += __shfl_xor(psum, 4, 16);
        psum += __shfl_xor(psum, 8, 16);
        float alpha = expf(m_row - m_new);
        l_row = l_row * alpha + psum;
        m_row = m_new;
        #pragma unroll
        for (int j = 0; j < 8; ++j) o[j] *= alpha;
        #pragma unroll
        for (int k = 0; k < 16; ++k) {
            float pk = __shfl(p, k, 16);
            #pragma unroll
            for (int j = 0; j < 8; ++j)
                o[j] += pk * Vs[k][tx * 8 + j];
        }
    }
    float inv_l = 1.0f / l_row;
    #pragma unroll
    for (int j = 0; j < 8; ++j)
        outbuf[(size_t)(q0 + ty) * 2048 + h * 128 + tx * 8 + j] = o[j] * inv_l;
}

extern "C" void kernel_launch(void* const* d_in, const int* in_sizes, int n_in,
                              void* d_out, int out_size, void* d_ws, size_t ws_size,
                              hipStream_t stream)
{
    (void)in_sizes; (void)n_in; (void)out_size; (void)ws_size;
    const float* hs   = (const float*)d_in[0];
    const float* Wqa  = (const float*)d_in[1];
    const float* qlnw = (const float*)d_in[2];
    const float* Wqb  = (const float*)d_in[3];
    const float* Wkva = (const float*)d_in[4];
    const float* klnw = (const float*)d_in[5];
    const float* Wkvb = (const float*)d_in[6];
    const float* Wo   = (const float*)d_in[7];
    float* out = (float*)d_out;

    float* qa   = (float*)d_ws;                        // S x 1536
    float* qbuf = qa   + (size_t)S_LEN * Q_LORA;       // S x 3072
    float* ckv  = qbuf + (size_t)S_LEN * 3072;         // S x 576
    float* kv   = ckv  + (size_t)S_LEN * 576;          // S x 4096
    float* aout = kv   + (size_t)S_LEN * 4096;         // S x 2048

    dim3 blk(16, 16);

    // 1. qa = hs @ Wqa   (2048 x 1536 x 2048)
    gemm_kernel<<<dim3(Q_LORA / 64, S_LEN / 64), blk, 0, stream>>>(
        hs, H_DIM, Wqa, qa, S_LEN, Q_LORA, H_DIM);
    // 2. rmsnorm(qa) in place
    rmsnorm_kernel<<<S_LEN, 256, 0, stream>>>(qa, Q_LORA, Q_LORA, qlnw);
    // 3. qbuf = qa @ Wqb (2048 x 3072 x 1536)
    gemm_kernel<<<dim3(3072 / 64, S_LEN / 64), blk, 0, stream>>>(
        qa, Q_LORA, Wqb, qbuf, S_LEN, NH * D_QK, Q_LORA);
    // 4. ckv = hs @ Wkva (2048 x 576 x 2048)
    gemm_kernel<<<dim3(576 / 64, S_LEN / 64), blk, 0, stream>>>(
        hs, H_DIM, Wkva, ckv, S_LEN, KV_LORA + D_ROPE, H_DIM);
    // 5. rmsnorm(ckv[:, :512]) in place, row stride 576
    rmsnorm_kernel<<<S_LEN, 256, 0, stream>>>(ckv, 576, KV_LORA, klnw);
    // 6. RoPE: q_pe (16 heads, offset 128 within each 192) and k_pe (cols 512..576)
    rope_kernel<<<(S_LEN * NH * 32 + 255) / 256, 256, 0, stream>>>(qbuf, 3072, D_QK, NH, D_NOPE);
    rope_kernel<<<(S_LEN * 32 + 255) / 256, 256, 0, stream>>>(ckv, 576, 0, 1, KV_LORA);
    // 7. kv = rmsnorm(ckv) @ Wkvb (2048 x 4096 x 512), A has lda=576
    gemm_kernel<<<dim3(4096 / 64, S_LEN / 64), blk, 0, stream>>>(
        ckv, 576, Wkvb, kv, S_LEN, NH * (D_NOPE + D_V), KV_LORA);
    // 8. attention
    attn_kernel<<<dim3(S_LEN / 16, NH), blk, 0, stream>>>(qbuf, kv, ckv, aout);
    // 9. out = aout @ Wo (2048 x 2048 x 2048)
    gemm_kernel<<<dim3(2048 / 64, S_LEN / 64), blk, 0, stream>>>(
        aout, NH * D_V, Wo, out, S_LEN, H_DIM, NH * D_V);
}

// Round 3
// 1484.555 us; speedup vs baseline: 2.2726x; 2.2726x over previous
//
#include <hip/hip_runtime.h>
#include <hip/hip_bf16.h>
#include <math.h>

#define S_LEN 2048
#define H_DIM 2048
#define NH 16
#define Q_LORA 1536
#define KV_LORA 512
#define D_NOPE 128
#define D_ROPE 64
#define D_V 128
#define D_QK 192

typedef unsigned short ushort_t;
typedef __attribute__((ext_vector_type(8))) short short8;
typedef __attribute__((ext_vector_type(4))) float f32x4;

__device__ __forceinline__ ushort_t f2bf(float f) {
    unsigned int u = __float_as_uint(f);
    u = (u + 0x7FFFu + ((u >> 16) & 1u)) >> 16;
    return (ushort_t)u;
}

// ---------------- fp32 VALU GEMM (unchanged from round 1) ----------------
__global__ __launch_bounds__(256) void gemm_kernel(
    const float* __restrict__ A, int lda,
    const float* __restrict__ B,
    float* __restrict__ C, int M, int N, int K)
{
    __shared__ float As[16][65];
    __shared__ float Bs[16][68];
    const int tx = threadIdx.x, ty = threadIdx.y;
    const int tid = ty * 16 + tx;
    const int m0 = blockIdx.y * 64, n0 = blockIdx.x * 64;
    float acc[4][4] = {};

    for (int k0 = 0; k0 < K; k0 += 16) {
        #pragma unroll
        for (int i = 0; i < 4; ++i) {
            int idx = tid + i * 256;
            int r = idx >> 4;
            int c = idx & 15;
            As[c][r] = A[(size_t)(m0 + r) * lda + k0 + c];
        }
        #pragma unroll
        for (int i = 0; i < 4; ++i) {
            int idx = tid + i * 256;
            int r = idx >> 6;
            int c = idx & 63;
            Bs[r][c] = B[(size_t)(k0 + r) * N + n0 + c];
        }
        __syncthreads();
        #pragma unroll
        for (int kk = 0; kk < 16; ++kk) {
            float a[4], b[4];
            #pragma unroll
            for (int i = 0; i < 4; ++i) a[i] = As[kk][ty * 4 + i];
            #pragma unroll
            for (int j = 0; j < 4; ++j) b[j] = Bs[kk][tx * 4 + j];
            #pragma unroll
            for (int i = 0; i < 4; ++i)
                #pragma unroll
                for (int j = 0; j < 4; ++j)
                    acc[i][j] += a[i] * b[j];
        }
        __syncthreads();
    }
    #pragma unroll
    for (int i = 0; i < 4; ++i)
        #pragma unroll
        for (int j = 0; j < 4; ++j)
            C[(size_t)(m0 + ty * 4 + i) * N + n0 + tx * 4 + j] = acc[i][j];
}

__global__ __launch_bounds__(256) void rmsnorm_kernel(
    float* __restrict__ X, int rowStride, int K,
    const float* __restrict__ w)
{
    __shared__ float red[4];
    float* x = X + (size_t)blockIdx.x * rowStride;
    float ss = 0.f;
    for (int i = threadIdx.x; i < K; i += 256) { float v = x[i]; ss += v * v; }
    #pragma unroll
    for (int off = 32; off > 0; off >>= 1) ss += __shfl_down(ss, off);
    int lane = threadIdx.x & 63, wid = threadIdx.x >> 6;
    if (lane == 0) red[wid] = ss;
    __syncthreads();
    float tot = red[0] + red[1] + red[2] + red[3];
    float rs = rsqrtf(tot / (float)K + 1e-6f);
    for (int i = threadIdx.x; i < K; i += 256)
        x[i] = x[i] * rs * w[i];
}

__global__ void rope_kernel(float* __restrict__ X, int rowStride, int headStride,
                            int nHeads, int dimOffset)
{
    int idx = blockIdx.x * 256 + threadIdx.x;
    int total = S_LEN * nHeads * 32;
    if (idx >= total) return;
    int i = idx & 31;
    int sh = idx >> 5;
    int hh = sh % nHeads;
    int s = sh / nHeads;
    float inv = powf(10000.0f, -(2.0f * i) / 64.0f);
    float ang = (float)s * inv;
    float c = cosf(ang), sn = sinf(ang);
    float* p = X + (size_t)s * rowStride + hh * headStride + dimOffset;
    float x1 = p[i], x2 = p[i + 32];
    p[i]      = x1 * c - x2 * sn;
    p[i + 32] = x2 * c + x1 * sn;
}

// ---------------- bf16 conversion for attention ----------------
// q16[h][s][192] <- qbuf[s][h*192+c]
__global__ __launch_bounds__(256) void conv_q_kernel(
    const float* __restrict__ qbuf, ushort_t* __restrict__ q16)
{
    int idx = blockIdx.x * 256 + threadIdx.x;
    if (idx >= NH * S_LEN * D_QK) return;
    int c = idx % D_QK;
    int t = idx / D_QK;
    int s = t & (S_LEN - 1);
    int h = t >> 11;
    q16[idx] = f2bf(qbuf[(size_t)s * (NH * D_QK) + h * D_QK + c]);
}

// k16[h][s][192]: c<128 from kv[s][h*256+c], c>=128 from ckv[s][512+(c-128)]
__global__ __launch_bounds__(256) void conv_k_kernel(
    const float* __restrict__ kv, const float* __restrict__ ckv,
    ushort_t* __restrict__ k16)
{
    int idx = blockIdx.x * 256 + threadIdx.x;
    if (idx >= NH * S_LEN * D_QK) return;
    int c = idx % D_QK;
    int t = idx / D_QK;
    int s = t & (S_LEN - 1);
    int h = t >> 11;
    float v;
    if (c < D_NOPE) v = kv[(size_t)s * 4096 + h * 256 + c];
    else            v = ckv[(size_t)s * 576 + KV_LORA + (c - D_NOPE)];
    k16[idx] = f2bf(v);
}

// v16t[h][dv][s] <- kv[s][h*256+128+dv]   (transposed store, coalesced read)
__global__ __launch_bounds__(256) void conv_v_kernel(
    const float* __restrict__ kv, ushort_t* __restrict__ v16t)
{
    int idx = blockIdx.x * 256 + threadIdx.x;
    if (idx >= NH * S_LEN * D_V) return;
    int dv = idx & (D_V - 1);
    int t = idx >> 7;
    int s = t & (S_LEN - 1);
    int h = t >> 11;
    v16t[(size_t)h * D_V * S_LEN + (size_t)dv * S_LEN + s] =
        f2bf(kv[(size_t)s * 4096 + h * 256 + D_NOPE + dv]);
}

// ---------------- MFMA flash attention ----------------
// Grid: (S/64, NH), 256 threads = 4 waves. Wave w handles q rows [q0+16w, q0+16w+16).
// q16/k16: [h][s][192] bf16, v16t: [h][dv=128][s=2048] bf16. Out: aout fp32 [s][h*128+dv].
__global__ __launch_bounds__(256) void mla_attn_kernel(
    const ushort_t* __restrict__ q16, const ushort_t* __restrict__ k16,
    const ushort_t* __restrict__ v16t, float* __restrict__ aout)
{
    __shared__ ushort_t Ps[4][16][40];  // per-wave P tile [q 16][key 32], stride 40 (80B, 16B-aligned rows, 2-way banks)
    const int h = blockIdx.y;
    const int q0 = blockIdx.x * 64;
    const int w = threadIdx.x >> 6;
    const int lane = threadIdx.x & 63;
    const int lm = lane & 15, quad = lane >> 4;
    const int qw = q0 + w * 16;
    const ushort_t* qh = q16 + (size_t)h * S_LEN * D_QK;
    const ushort_t* kh = k16 + (size_t)h * S_LEN * D_QK;
    const ushort_t* vh = v16t + (size_t)h * D_V * S_LEN;

    // Q fragments: A[m=lm][k=quad*8+j], 6 chunks of K=32 over D_QK=192
    short8 qf[6];
    #pragma unroll
    for (int f = 0; f < 6; ++f)
        qf[f] = *(const short8*)(qh + (size_t)(qw + lm) * D_QK + f * 32 + quad * 8);

    f32x4 O[8];
    #pragma unroll
    for (int c = 0; c < 8; ++c) O[c] = (f32x4){0.f, 0.f, 0.f, 0.f};
    float m_[4] = {-1e30f, -1e30f, -1e30f, -1e30f};
    float l_[4] = {0.f, 0.f, 0.f, 0.f};
    const float scale = 0.07216878364870322f;  // 192^-0.5

    const int kend = qw + 16;  // keys needed: <= qw+15
    for (int k0 = 0; k0 < kend; k0 += 32) {
        // ---- S = Q K^T for 32 keys (two 16x16 tiles) ----
        f32x4 s0 = {0.f, 0.f, 0.f, 0.f}, s1 = {0.f, 0.f, 0.f, 0.f};
        const ushort_t* kr0 = kh + (size_t)(k0 + lm) * D_QK + quad * 8;
        const ushort_t* kr1 = kr0 + 16 * D_QK;
        #pragma unroll
        for (int f = 0; f < 6; ++f) {
            short8 kf0 = *(const short8*)(kr0 + f * 32);
            short8 kf1 = *(const short8*)(kr1 + f * 32);
            s0 = __builtin_amdgcn_mfma_f32_16x16x32_bf16(qf[f], kf0, s0, 0, 0, 0);
            s1 = __builtin_amdgcn_mfma_f32_16x16x32_bf16(qf[f], kf1, s1, 0, 0, 0);
        }
        // ---- online softmax in C layout: row=(quad*4+r), col=lm ----
        #pragma unroll
        for (int r = 0; r < 4; ++r) {
            int qrow = qw + quad * 4 + r;
            float a = (k0 + lm <= qrow)      ? s0[r] * scale : -1e30f;
            float b = (k0 + 16 + lm <= qrow) ? s1[r] * scale : -1e30f;
            float mx = fmaxf(a, b);
            mx = fmaxf(mx, __shfl_xor(mx, 1));
            mx = fmaxf(mx, __shfl_xor(mx, 2));
            mx = fmaxf(mx, __shfl_xor(mx, 4));
            mx = fmaxf(mx, __shfl_xor(mx, 8));
            float mn = fmaxf(m_[r], mx);
            float p0 = __expf(a - mn);
            float p1 = __expf(b - mn);
            float alpha = __expf(m_[r] - mn);
            float ps = p0 + p1;
            ps += __shfl_xor(ps, 1);
            ps += __shfl_xor(ps, 2);
            ps += __shfl_xor(ps, 4);
            ps += __shfl_xor(ps, 8);
            l_[r] = l_[r] * alpha + ps;
            m_[r] = mn;
            #pragma unroll
            for (int c = 0; c < 8; ++c) O[c][r] *= alpha;
            Ps[w][quad * 4 + r][lm]      = f2bf(p0);
            Ps[w][quad * 4 + r][16 + lm] = f2bf(p1);
        }
        // wave-local LDS round-trip: C layout -> A layout (no cross-wave sharing)
        asm volatile("s_waitcnt lgkmcnt(0)" ::: "memory");
        short8 pf = *(const short8*)&Ps[w][lm][quad * 8];
        // ---- O += P V : A=P[16q x 32key], B=V[32key x 16dv] per chunk ----
        const ushort_t* vr = vh + (size_t)lm * S_LEN + k0 + quad * 8;
        #pragma unroll
        for (int c = 0; c < 8; ++c) {
            short8 vf = *(const short8*)(vr + (size_t)c * 16 * S_LEN);
            O[c] = __builtin_amdgcn_mfma_f32_16x16x32_bf16(pf, vf, O[c], 0, 0, 0);
        }
    }
    // epilogue: divide by l, store fp32
    #pragma unroll
    for (int c = 0; c < 8; ++c) {
        #pragma unroll
        for (int r = 0; r < 4; ++r) {
            int qrow = qw + quad * 4 + r;
            aout[(size_t)qrow * (NH * D_V) + h * D_V + c * 16 + lm] = O[c][r] / l_[r];
        }
    }
}

extern "C" void kernel_launch(void* const* d_in, const int* in_sizes, int n_in,
                              void* d_out, int out_size, void* d_ws, size_t ws_size,
                              hipStream_t stream)
{
    (void)in_sizes; (void)n_in; (void)out_size; (void)ws_size;
    const float* hs   = (const float*)d_in[0];
    const float* Wqa  = (const float*)d_in[1];
    const float* qlnw = (const float*)d_in[2];
    const float* Wqb  = (const float*)d_in[3];
    const float* Wkva = (const float*)d_in[4];
    const float* klnw = (const float*)d_in[5];
    const float* Wkvb = (const float*)d_in[6];
    const float* Wo   = (const float*)d_in[7];
    float* out = (float*)d_out;

    float* qa   = (float*)d_ws;                        // S x 1536
    float* qbuf = qa   + (size_t)S_LEN * Q_LORA;       // S x 3072
    float* ckv  = qbuf + (size_t)S_LEN * 3072;         // S x 576
    float* kv   = ckv  + (size_t)S_LEN * 576;          // S x 4096
    float* aout = kv   + (size_t)S_LEN * 4096;         // S x 2048
    ushort_t* q16  = (ushort_t*)(aout + (size_t)S_LEN * 2048);   // 16x2048x192
    ushort_t* k16  = q16 + (size_t)NH * S_LEN * D_QK;            // 16x2048x192
    ushort_t* v16t = k16 + (size_t)NH * S_LEN * D_QK;            // 16x128x2048

    dim3 blk(16, 16);

    // 1. qa = hs @ Wqa   (2048 x 1536 x 2048)
    gemm_kernel<<<dim3(Q_LORA / 64, S_LEN / 64), blk, 0, stream>>>(
        hs, H_DIM, Wqa, qa, S_LEN, Q_LORA, H_DIM);
    // 2. rmsnorm(qa)
    rmsnorm_kernel<<<S_LEN, 256, 0, stream>>>(qa, Q_LORA, Q_LORA, qlnw);
    // 3. qbuf = qa @ Wqb (2048 x 3072 x 1536)
    gemm_kernel<<<dim3(3072 / 64, S_LEN / 64), blk, 0, stream>>>(
        qa, Q_LORA, Wqb, qbuf, S_LEN, NH * D_QK, Q_LORA);
    // 4. ckv = hs @ Wkva (2048 x 576 x 2048)
    gemm_kernel<<<dim3(576 / 64, S_LEN / 64), blk, 0, stream>>>(
        hs, H_DIM, Wkva, ckv, S_LEN, KV_LORA + D_ROPE, H_DIM);
    // 5. rmsnorm(ckv[:, :512])
    rmsnorm_kernel<<<S_LEN, 256, 0, stream>>>(ckv, 576, KV_LORA, klnw);
    // 6. RoPE
    rope_kernel<<<(S_LEN * NH * 32 + 255) / 256, 256, 0, stream>>>(qbuf, 3072, D_QK, NH, D_NOPE);
    rope_kernel<<<(S_LEN * 32 + 255) / 256, 256, 0, stream>>>(ckv, 576, 0, 1, KV_LORA);
    // 7. kv = rmsnorm(ckv) @ Wkvb (2048 x 4096 x 512)
    gemm_kernel<<<dim3(4096 / 64, S_LEN / 64), blk, 0, stream>>>(
        ckv, 576, Wkvb, kv, S_LEN, NH * (D_NOPE + D_V), KV_LORA);
    // 8. bf16 conversion for attention
    conv_q_kernel<<<(NH * S_LEN * D_QK + 255) / 256, 256, 0, stream>>>(qbuf, q16);
    conv_k_kernel<<<(NH * S_LEN * D_QK + 255) / 256, 256, 0, stream>>>(kv, ckv, k16);
    conv_v_kernel<<<(NH * S_LEN * D_V + 255) / 256, 256, 0, stream>>>(kv, v16t);
    // 9. MFMA flash attention
    mla_attn_kernel<<<dim3(S_LEN / 64, NH), 256, 0, stream>>>(q16, k16, v16t, aout);
    // 10. out = aout @ Wo (2048 x 2048 x 2048)
    gemm_kernel<<<dim3(2048 / 64, S_LEN / 64), blk, 0, stream>>>(
        aout, NH * D_V, Wo, out, S_LEN, H_DIM, NH * D_V);
}

// Round 4
// 647.198 us; speedup vs baseline: 5.2129x; 2.2938x over previous
//
#include <hip/hip_runtime.h>
#include <hip/hip_bf16.h>
#include <math.h>

#define S_LEN 2048
#define H_DIM 2048
#define NH 16
#define Q_LORA 1536
#define KV_LORA 512
#define D_NOPE 128
#define D_ROPE 64
#define D_V 128
#define D_QK 192

typedef unsigned short ushort_t;
typedef __attribute__((ext_vector_type(8))) short short8;
typedef __attribute__((ext_vector_type(4))) float f32x4;

__device__ __forceinline__ ushort_t f2bf(float f) {
    unsigned int u = __float_as_uint(f);
    u = (u + 0x7FFFu + ((u >> 16) & 1u)) >> 16;
    return (ushort_t)u;
}
__device__ __forceinline__ float bf2f(ushort_t u) {
    return __uint_as_float(((unsigned int)u) << 16);
}

__device__ __forceinline__ void storeC(float* p, float v) { *p = v; }
__device__ __forceinline__ void storeC(ushort_t* p, float v) { *p = f2bf(v); }

__device__ __forceinline__ void gload_lds16(const ushort_t* g, ushort_t* l) {
    __builtin_amdgcn_global_load_lds(
        (const __attribute__((address_space(1))) unsigned int*)(const void*)g,
        (__attribute__((address_space(3))) unsigned int*)(void*)l, 16, 0, 0);
}

// ---------------- fp32 -> bf16 elementwise (n % 4 == 0) ----------------
__global__ __launch_bounds__(256) void conv_f32_bf16(
    const float* __restrict__ X, ushort_t* __restrict__ Y, int n)
{
    int base = (blockIdx.x * 256 + threadIdx.x) * 4;
    if (base >= n) return;
    float4 v = *(const float4*)(X + base);
    Y[base + 0] = f2bf(v.x);
    Y[base + 1] = f2bf(v.y);
    Y[base + 2] = f2bf(v.z);
    Y[base + 3] = f2bf(v.w);
}

// ------------- weight transpose+convert: W[K][N] f32 -> Wt[Npad][K] bf16 -------------
// grid (Npad/32, K/32), 256 threads. Rows n>=N are zero-filled.
__global__ __launch_bounds__(256) void convT_kernel(
    const float* __restrict__ W, ushort_t* __restrict__ Wt, int K, int N)
{
    __shared__ float tile[32][33];
    const int k0 = blockIdx.y * 32, n0 = blockIdx.x * 32;
    const int tr = threadIdx.x >> 5, tc = threadIdx.x & 31;
    #pragma unroll
    for (int i = 0; i < 4; ++i) {
        int r = tr + i * 8;
        float v = 0.f;
        if (n0 + tc < N) v = W[(size_t)(k0 + r) * N + n0 + tc];
        tile[r][tc] = v;
    }
    __syncthreads();
    #pragma unroll
    for (int i = 0; i < 4; ++i) {
        int r = tr + i * 8;  // n-index within tile
        Wt[(size_t)(n0 + r) * K + k0 + tc] = f2bf(tile[tc][r]);
    }
}

// ---------------- bf16 rmsnorm: X[row][0..K) (stride in) -> Y (stride out) ----------------
__global__ __launch_bounds__(256) void rmsnorm_bf16_kernel(
    const ushort_t* __restrict__ X, int inStride,
    ushort_t* __restrict__ Y, int outStride, int K, const float* __restrict__ w)
{
    __shared__ float red[4];
    const ushort_t* x = X + (size_t)blockIdx.x * inStride;
    ushort_t* y = Y + (size_t)blockIdx.x * outStride;
    float ss = 0.f;
    for (int i = threadIdx.x; i < K; i += 256) { float v = bf2f(x[i]); ss += v * v; }
    #pragma unroll
    for (int off = 32; off > 0; off >>= 1) ss += __shfl_down(ss, off);
    int lane = threadIdx.x & 63, wid = threadIdx.x >> 6;
    if (lane == 0) red[wid] = ss;
    __syncthreads();
    float tot = red[0] + red[1] + red[2] + red[3];
    float rs = rsqrtf(tot / (float)K + 1e-6f);
    for (int i = threadIdx.x; i < K; i += 256)
        y[i] = f2bf(bf2f(x[i]) * rs * w[i]);
}

// ---------------- bf16 RoPE ----------------
__global__ void rope_bf16_kernel(
    const ushort_t* __restrict__ src, int srcStride, int srcOff,
    ushort_t* __restrict__ dst, int dstStride, int dstOff,
    int headStride, int nHeads)
{
    int idx = blockIdx.x * 256 + threadIdx.x;
    if (idx >= S_LEN * nHeads * 32) return;
    int i = idx & 31;
    int sh = idx >> 5;
    int hh = sh % nHeads;
    int s = sh / nHeads;
    float inv = powf(10000.0f, -(2.0f * i) / 64.0f);
    float ang = (float)s * inv;
    float c = cosf(ang), sn = sinf(ang);
    const ushort_t* p = src + (size_t)s * srcStride + hh * headStride + srcOff;
    ushort_t* q = dst + (size_t)s * dstStride + hh * headStride + dstOff;
    float x1 = bf2f(p[i]), x2 = bf2f(p[i + 32]);
    q[i]      = f2bf(x1 * c - x2 * sn);
    q[i + 32] = f2bf(x2 * c + x1 * sn);
}

// ---------------- V transpose: kv16[s][h*256+128+dv] -> v16t[h][dv][s] ----------------
// grid (S/32, 128/32, NH)
__global__ __launch_bounds__(256) void conv_vT_kernel(
    const ushort_t* __restrict__ kv, ushort_t* __restrict__ v16t)
{
    __shared__ ushort_t tile[32][33];
    const int h = blockIdx.z;
    const int s0 = blockIdx.x * 32, d0 = blockIdx.y * 32;
    const int tr = threadIdx.x >> 5, tc = threadIdx.x & 31;
    #pragma unroll
    for (int i = 0; i < 4; ++i) {
        int r = tr + i * 8;  // s
        tile[r][tc] = kv[(size_t)(s0 + r) * 4096 + h * 256 + D_NOPE + d0 + tc];
    }
    __syncthreads();
    #pragma unroll
    for (int i = 0; i < 4; ++i) {
        int r = tr + i * 8;  // dv
        v16t[(size_t)h * D_V * S_LEN + (size_t)(d0 + r) * S_LEN + s0 + tc] = tile[tc][r];
    }
}

// ---------------- m97-style MFMA GEMM: C[M][N] = A[M][K] * Bt[N][K]^T ----------------
// 128x128 tile, BK=32, 256 threads = 4 waves in 2x2, each wave 64x64 (4x4 MFMA tiles).
template <typename CT>
__global__ __launch_bounds__(256) void mfma_gemm_bt(
    const ushort_t* __restrict__ A, const ushort_t* __restrict__ Bt,
    CT* __restrict__ C, int N, int K)
{
    __shared__ ushort_t Al[128 * 32];
    __shared__ ushort_t Bl[128 * 32];
    const int m0 = blockIdx.y * 128, n0 = blockIdx.x * 128;
    const int tid = threadIdx.x;
    const int lane = tid & 63;
    const int w = tid >> 6;
    const int lm = lane & 15, quad = lane >> 4;
    const int wr = w >> 1, wc = w & 1;

    f32x4 acc[4][4];
    #pragma unroll
    for (int a = 0; a < 4; ++a)
        #pragma unroll
        for (int b = 0; b < 4; ++b) acc[a][b] = (f32x4){0.f, 0.f, 0.f, 0.f};

    const int rrow = tid >> 2;            // 0..63
    const int rcol = (tid & 3) * 8;       // element offset in K-slab

    for (int k0 = 0; k0 < K; k0 += 32) {
        __syncthreads();  // previous iter's LDS reads done
        #pragma unroll
        for (int i = 0; i < 2; ++i) {
            int row = i * 64 + rrow;
            gload_lds16(A  + (size_t)(m0 + row) * K + k0 + rcol, Al + (i * 256 + tid) * 8);
            gload_lds16(Bt + (size_t)(n0 + row) * K + k0 + rcol, Bl + (i * 256 + tid) * 8);
        }
        __syncthreads();  // staging visible (compiler drains vmcnt)

        short8 af[4], bf[4];
        #pragma unroll
        for (int t = 0; t < 4; ++t) {
            af[t] = *(const short8*)(Al + (wr * 64 + t * 16 + lm) * 32 + quad * 8);
            bf[t] = *(const short8*)(Bl + (wc * 64 + t * 16 + lm) * 32 + quad * 8);
        }
        #pragma unroll
        for (int mt = 0; mt < 4; ++mt)
            #pragma unroll
            for (int nt = 0; nt < 4; ++nt)
                acc[mt][nt] = __builtin_amdgcn_mfma_f32_16x16x32_bf16(
                    af[mt], bf[nt], acc[mt][nt], 0, 0, 0);
    }

    #pragma unroll
    for (int mt = 0; mt < 4; ++mt)
        #pragma unroll
        for (int nt = 0; nt < 4; ++nt)
            #pragma unroll
            for (int r = 0; r < 4; ++r) {
                int row = m0 + wr * 64 + mt * 16 + quad * 4 + r;
                int col = n0 + wc * 64 + nt * 16 + lm;
                storeC(&C[(size_t)row * N + col], acc[mt][nt][r]);
            }
}

// ---------------- MFMA flash attention (bf16 sources) ----------------
// qb: [S][3072], kvb: [S][4096], kpe: [S][64], v16t: [NH][128][S], aout16: [S][2048]
__global__ __launch_bounds__(256) void mla_attn_kernel(
    const ushort_t* __restrict__ qb, const ushort_t* __restrict__ kvb,
    const ushort_t* __restrict__ kpe, const ushort_t* __restrict__ v16t,
    ushort_t* __restrict__ aout16)
{
    __shared__ ushort_t Ps[4][16][40];
    const int h = blockIdx.y;
    const int q0 = blockIdx.x * 64;
    const int w = threadIdx.x >> 6;
    const int lane = threadIdx.x & 63;
    const int lm = lane & 15, quad = lane >> 4;
    const int qw = q0 + w * 16;
    const ushort_t* vh = v16t + (size_t)h * D_V * S_LEN;

    short8 qf[6];
    #pragma unroll
    for (int f = 0; f < 6; ++f)
        qf[f] = *(const short8*)(qb + (size_t)(qw + lm) * 3072 + h * 192 + f * 32 + quad * 8);

    f32x4 O[8];
    #pragma unroll
    for (int c = 0; c < 8; ++c) O[c] = (f32x4){0.f, 0.f, 0.f, 0.f};
    float m_[4] = {-1e30f, -1e30f, -1e30f, -1e30f};
    float l_[4] = {0.f, 0.f, 0.f, 0.f};
    const float scale = 0.07216878364870322f;  // 192^-0.5

    const int kend = qw + 16;
    for (int k0 = 0; k0 < kend; k0 += 32) {
        f32x4 s0 = {0.f, 0.f, 0.f, 0.f}, s1 = {0.f, 0.f, 0.f, 0.f};
        const ushort_t* kr0 = kvb + (size_t)(k0 + lm) * 4096 + h * 256 + quad * 8;
        const ushort_t* kr1 = kr0 + 16 * 4096;
        #pragma unroll
        for (int f = 0; f < 4; ++f) {
            short8 kf0 = *(const short8*)(kr0 + f * 32);
            short8 kf1 = *(const short8*)(kr1 + f * 32);
            s0 = __builtin_amdgcn_mfma_f32_16x16x32_bf16(qf[f], kf0, s0, 0, 0, 0);
            s1 = __builtin_amdgcn_mfma_f32_16x16x32_bf16(qf[f], kf1, s1, 0, 0, 0);
        }
        const ushort_t* pr0 = kpe + (size_t)(k0 + lm) * 64 + quad * 8;
        #pragma unroll
        for (int f = 0; f < 2; ++f) {
            short8 kf0 = *(const short8*)(pr0 + f * 32);
            short8 kf1 = *(const short8*)(pr0 + 16 * 64 + f * 32);
            s0 = __builtin_amdgcn_mfma_f32_16x16x32_bf16(qf[4 + f], kf0, s0, 0, 0, 0);
            s1 = __builtin_amdgcn_mfma_f32_16x16x32_bf16(qf[4 + f], kf1, s1, 0, 0, 0);
        }
        #pragma unroll
        for (int r = 0; r < 4; ++r) {
            int qrow = qw + quad * 4 + r;
            float a = (k0 + lm <= qrow)      ? s0[r] * scale : -1e30f;
            float b = (k0 + 16 + lm <= qrow) ? s1[r] * scale : -1e30f;
            float mx = fmaxf(a, b);
            mx = fmaxf(mx, __shfl_xor(mx, 1));
            mx = fmaxf(mx, __shfl_xor(mx, 2));
            mx = fmaxf(mx, __shfl_xor(mx, 4));
            mx = fmaxf(mx, __shfl_xor(mx, 8));
            float mn = fmaxf(m_[r], mx);
            float p0 = __expf(a - mn);
            float p1 = __expf(b - mn);
            float alpha = __expf(m_[r] - mn);
            float ps = p0 + p1;
            ps += __shfl_xor(ps, 1);
            ps += __shfl_xor(ps, 2);
            ps += __shfl_xor(ps, 4);
            ps += __shfl_xor(ps, 8);
            l_[r] = l_[r] * alpha + ps;
            m_[r] = mn;
            #pragma unroll
            for (int c = 0; c < 8; ++c) O[c][r] *= alpha;
            Ps[w][quad * 4 + r][lm]      = f2bf(p0);
            Ps[w][quad * 4 + r][16 + lm] = f2bf(p1);
        }
        asm volatile("s_waitcnt lgkmcnt(0)" ::: "memory");
        short8 pf = *(const short8*)&Ps[w][lm][quad * 8];
        const ushort_t* vr = vh + (size_t)lm * S_LEN + k0 + quad * 8;
        #pragma unroll
        for (int c = 0; c < 8; ++c) {
            short8 vf = *(const short8*)(vr + (size_t)c * 16 * S_LEN);
            O[c] = __builtin_amdgcn_mfma_f32_16x16x32_bf16(pf, vf, O[c], 0, 0, 0);
        }
    }
    #pragma unroll
    for (int c = 0; c < 8; ++c)
        #pragma unroll
        for (int r = 0; r < 4; ++r) {
            int qrow = qw + quad * 4 + r;
            aout16[(size_t)qrow * 2048 + h * D_V + c * 16 + lm] = f2bf(O[c][r] / l_[r]);
        }
}

extern "C" void kernel_launch(void* const* d_in, const int* in_sizes, int n_in,
                              void* d_out, int out_size, void* d_ws, size_t ws_size,
                              hipStream_t stream)
{
    (void)in_sizes; (void)n_in; (void)out_size; (void)ws_size;
    const float* hs   = (const float*)d_in[0];
    const float* Wqa  = (const float*)d_in[1];
    const float* qlnw = (const float*)d_in[2];
    const float* Wqb  = (const float*)d_in[3];
    const float* Wkva = (const float*)d_in[4];
    const float* klnw = (const float*)d_in[5];
    const float* Wkvb = (const float*)d_in[6];
    const float* Wo   = (const float*)d_in[7];
    float* out = (float*)d_out;

    ushort_t* p = (ushort_t*)d_ws;
    ushort_t* hs16   = p; p += (size_t)S_LEN * H_DIM;        // 2048x2048
    ushort_t* WqaT   = p; p += (size_t)Q_LORA * H_DIM;       // 1536x2048
    ushort_t* WqbT   = p; p += (size_t)3072 * Q_LORA;        // 3072x1536
    ushort_t* WkvaT  = p; p += (size_t)640 * H_DIM;          // 640x2048 (padded from 576)
    ushort_t* WkvbT  = p; p += (size_t)4096 * KV_LORA;       // 4096x512
    ushort_t* WoT    = p; p += (size_t)H_DIM * H_DIM;        // 2048x2048
    ushort_t* qa16r  = p; p += (size_t)S_LEN * Q_LORA;       // 2048x1536
    ushort_t* qa16   = p; p += (size_t)S_LEN * Q_LORA;       // 2048x1536
    ushort_t* qbuf16 = p; p += (size_t)S_LEN * 3072;         // 2048x3072
    ushort_t* ckv16r = p; p += (size_t)S_LEN * 640;          // 2048x640
    ushort_t* ckv16n = p; p += (size_t)S_LEN * KV_LORA;      // 2048x512
    ushort_t* kpe16  = p; p += (size_t)S_LEN * D_ROPE;       // 2048x64
    ushort_t* kv16   = p; p += (size_t)S_LEN * 4096;         // 2048x4096
    ushort_t* v16t   = p; p += (size_t)NH * D_V * S_LEN;     // 16x128x2048
    ushort_t* aout16 = p; p += (size_t)S_LEN * 2048;         // 2048x2048

    // 0. conversions
    conv_f32_bf16<<<(S_LEN * H_DIM / 4 + 255) / 256, 256, 0, stream>>>(hs, hs16, S_LEN * H_DIM);
    convT_kernel<<<dim3(Q_LORA / 32, H_DIM / 32), 256, 0, stream>>>(Wqa, WqaT, H_DIM, Q_LORA);
    convT_kernel<<<dim3(3072 / 32, Q_LORA / 32), 256, 0, stream>>>(Wqb, WqbT, Q_LORA, 3072);
    convT_kernel<<<dim3(640 / 32, H_DIM / 32), 256, 0, stream>>>(Wkva, WkvaT, H_DIM, 576);
    convT_kernel<<<dim3(4096 / 32, KV_LORA / 32), 256, 0, stream>>>(Wkvb, WkvbT, KV_LORA, 4096);
    convT_kernel<<<dim3(H_DIM / 32, H_DIM / 32), 256, 0, stream>>>(Wo, WoT, H_DIM, H_DIM);

    // 1. qa16r = hs16 @ WqaT^T   [2048 x 1536, K=2048]
    mfma_gemm_bt<ushort_t><<<dim3(Q_LORA / 128, S_LEN / 128), 256, 0, stream>>>(
        hs16, WqaT, qa16r, Q_LORA, H_DIM);
    // 2. rmsnorm
    rmsnorm_bf16_kernel<<<S_LEN, 256, 0, stream>>>(qa16r, Q_LORA, qa16, Q_LORA, Q_LORA, qlnw);
    // 3. qbuf16 = qa16 @ WqbT^T  [2048 x 3072, K=1536]
    mfma_gemm_bt<ushort_t><<<dim3(3072 / 128, S_LEN / 128), 256, 0, stream>>>(
        qa16, WqbT, qbuf16, 3072, Q_LORA);
    // 4. ckv16r = hs16 @ WkvaT^T [2048 x 640, K=2048]
    mfma_gemm_bt<ushort_t><<<dim3(640 / 128, S_LEN / 128), 256, 0, stream>>>(
        hs16, WkvaT, ckv16r, 640, H_DIM);
    // 5. rmsnorm ckv (cols 0..512, stride 640 -> packed 512)
    rmsnorm_bf16_kernel<<<S_LEN, 256, 0, stream>>>(ckv16r, 640, ckv16n, KV_LORA, KV_LORA, klnw);
    // 6. RoPE: q (in place on qbuf16) and k (ckv16r cols 512.. -> kpe16)
    rope_bf16_kernel<<<(S_LEN * NH * 32 + 255) / 256, 256, 0, stream>>>(
        qbuf16, 3072, D_NOPE, qbuf16, 3072, D_NOPE, D_QK, NH);
    rope_bf16_kernel<<<(S_LEN * 32 + 255) / 256, 256, 0, stream>>>(
        ckv16r, 640, KV_LORA, kpe16, D_ROPE, 0, 0, 1);
    // 7. kv16 = ckv16n @ WkvbT^T [2048 x 4096, K=512]
    mfma_gemm_bt<ushort_t><<<dim3(4096 / 128, S_LEN / 128), 256, 0, stream>>>(
        ckv16n, WkvbT, kv16, 4096, KV_LORA);
    // 8. V transpose
    conv_vT_kernel<<<dim3(S_LEN / 32, D_V / 32, NH), 256, 0, stream>>>(kv16, v16t);
    // 9. attention
    mla_attn_kernel<<<dim3(S_LEN / 64, NH), 256, 0, stream>>>(qbuf16, kv16, kpe16, v16t, aout16);
    // 10. out = aout16 @ WoT^T [2048 x 2048, K=2048], fp32 store
    mfma_gemm_bt<float><<<dim3(H_DIM / 128, S_LEN / 128), 256, 0, stream>>>(
        aout16, WoT, out, H_DIM, H_DIM);
}

// Round 5
// 590.163 us; speedup vs baseline: 5.7167x; 1.0966x over previous
//
#include <hip/hip_runtime.h>
#include <hip/hip_bf16.h>
#include <math.h>

#define S_LEN 2048
#define H_DIM 2048
#define NH 16
#define Q_LORA 1536
#define KV_LORA 512
#define D_NOPE 128
#define D_ROPE 64
#define D_V 128
#define D_QK 192

typedef unsigned short ushort_t;
typedef __attribute__((ext_vector_type(8))) short short8;
typedef __attribute__((ext_vector_type(4))) float f32x4;

__device__ __forceinline__ ushort_t f2bf(float f) {
    unsigned int u = __float_as_uint(f);
    u = (u + 0x7FFFu + ((u >> 16) & 1u)) >> 16;
    return (ushort_t)u;
}
__device__ __forceinline__ float bf2f(ushort_t u) {
    return __uint_as_float(((unsigned int)u) << 16);
}

__device__ __forceinline__ void storeC(float* p, float v) { *p = v; }
__device__ __forceinline__ void storeC(ushort_t* p, float v) { *p = f2bf(v); }

__device__ __forceinline__ void gload_lds16(const ushort_t* g, ushort_t* l) {
    __builtin_amdgcn_global_load_lds(
        (const __attribute__((address_space(1))) unsigned int*)(const void*)g,
        (__attribute__((address_space(3))) unsigned int*)(void*)l, 16, 0, 0);
}

// ---------------- fp32 -> bf16 elementwise (n % 4 == 0) ----------------
__global__ __launch_bounds__(256) void conv_f32_bf16(
    const float* __restrict__ X, ushort_t* __restrict__ Y, int n)
{
    int base = (blockIdx.x * 256 + threadIdx.x) * 4;
    if (base >= n) return;
    float4 v = *(const float4*)(X + base);
    Y[base + 0] = f2bf(v.x);
    Y[base + 1] = f2bf(v.y);
    Y[base + 2] = f2bf(v.z);
    Y[base + 3] = f2bf(v.w);
}

// ------------- weight transpose+convert: W[K][N] f32 -> Wt[Npad][K] bf16 -------------
__global__ __launch_bounds__(256) void convT_kernel(
    const float* __restrict__ W, ushort_t* __restrict__ Wt, int K, int N)
{
    __shared__ float tile[32][33];
    const int k0 = blockIdx.y * 32, n0 = blockIdx.x * 32;
    const int tr = threadIdx.x >> 5, tc = threadIdx.x & 31;
    #pragma unroll
    for (int i = 0; i < 4; ++i) {
        int r = tr + i * 8;
        float v = 0.f;
        if (n0 + tc < N) v = W[(size_t)(k0 + r) * N + n0 + tc];
        tile[r][tc] = v;
    }
    __syncthreads();
    #pragma unroll
    for (int i = 0; i < 4; ++i) {
        int r = tr + i * 8;  // n-index within tile
        Wt[(size_t)(n0 + r) * K + k0 + tc] = f2bf(tile[tc][r]);
    }
}

// ---------------- bf16 rmsnorm ----------------
__global__ __launch_bounds__(256) void rmsnorm_bf16_kernel(
    const ushort_t* __restrict__ X, int inStride,
    ushort_t* __restrict__ Y, int outStride, int K, const float* __restrict__ w)
{
    __shared__ float red[4];
    const ushort_t* x = X + (size_t)blockIdx.x * inStride;
    ushort_t* y = Y + (size_t)blockIdx.x * outStride;
    float ss = 0.f;
    for (int i = threadIdx.x; i < K; i += 256) { float v = bf2f(x[i]); ss += v * v; }
    #pragma unroll
    for (int off = 32; off > 0; off >>= 1) ss += __shfl_down(ss, off);
    int lane = threadIdx.x & 63, wid = threadIdx.x >> 6;
    if (lane == 0) red[wid] = ss;
    __syncthreads();
    float tot = red[0] + red[1] + red[2] + red[3];
    float rs = rsqrtf(tot / (float)K + 1e-6f);
    for (int i = threadIdx.x; i < K; i += 256)
        y[i] = f2bf(bf2f(x[i]) * rs * w[i]);
}

// ---------------- bf16 RoPE ----------------
__global__ void rope_bf16_kernel(
    const ushort_t* __restrict__ src, int srcStride, int srcOff,
    ushort_t* __restrict__ dst, int dstStride, int dstOff,
    int headStride, int nHeads)
{
    int idx = blockIdx.x * 256 + threadIdx.x;
    if (idx >= S_LEN * nHeads * 32) return;
    int i = idx & 31;
    int sh = idx >> 5;
    int hh = sh % nHeads;
    int s = sh / nHeads;
    float inv = powf(10000.0f, -(2.0f * i) / 64.0f);
    float ang = (float)s * inv;
    float c = cosf(ang), sn = sinf(ang);
    const ushort_t* p = src + (size_t)s * srcStride + hh * headStride + srcOff;
    ushort_t* q = dst + (size_t)s * dstStride + hh * headStride + dstOff;
    float x1 = bf2f(p[i]), x2 = bf2f(p[i + 32]);
    q[i]      = f2bf(x1 * c - x2 * sn);
    q[i + 32] = f2bf(x2 * c + x1 * sn);
}

// ---------------- V transpose: kv16[s][h*256+128+dv] -> v16t[h][dv][s] ----------------
__global__ __launch_bounds__(256) void conv_vT_kernel(
    const ushort_t* __restrict__ kv, ushort_t* __restrict__ v16t)
{
    __shared__ ushort_t tile[32][33];
    const int h = blockIdx.z;
    const int s0 = blockIdx.x * 32, d0 = blockIdx.y * 32;
    const int tr = threadIdx.x >> 5, tc = threadIdx.x & 31;
    #pragma unroll
    for (int i = 0; i < 4; ++i) {
        int r = tr + i * 8;  // s
        tile[r][tc] = kv[(size_t)(s0 + r) * 4096 + h * 256 + D_NOPE + d0 + tc];
    }
    __syncthreads();
    #pragma unroll
    for (int i = 0; i < 4; ++i) {
        int r = tr + i * 8;  // dv
        v16t[(size_t)h * D_V * S_LEN + (size_t)(d0 + r) * S_LEN + s0 + tc] = tile[tc][r];
    }
}

// ---------------- m97-style MFMA GEMM: C[M][N] = A[M][K] * Bt[N][K]^T ----------------
template <typename CT>
__global__ __launch_bounds__(256) void mfma_gemm_bt(
    const ushort_t* __restrict__ A, const ushort_t* __restrict__ Bt,
    CT* __restrict__ C, int N, int K)
{
    __shared__ ushort_t Al[128 * 32];
    __shared__ ushort_t Bl[128 * 32];
    const int m0 = blockIdx.y * 128, n0 = blockIdx.x * 128;
    const int tid = threadIdx.x;
    const int lane = tid & 63;
    const int w = tid >> 6;
    const int lm = lane & 15, quad = lane >> 4;
    const int wr = w >> 1, wc = w & 1;

    f32x4 acc[4][4];
    #pragma unroll
    for (int a = 0; a < 4; ++a)
        #pragma unroll
        for (int b = 0; b < 4; ++b) acc[a][b] = (f32x4){0.f, 0.f, 0.f, 0.f};

    const int rrow = tid >> 2;
    const int rcol = (tid & 3) * 8;

    for (int k0 = 0; k0 < K; k0 += 32) {
        __syncthreads();
        #pragma unroll
        for (int i = 0; i < 2; ++i) {
            int row = i * 64 + rrow;
            gload_lds16(A  + (size_t)(m0 + row) * K + k0 + rcol, Al + (i * 256 + tid) * 8);
            gload_lds16(Bt + (size_t)(n0 + row) * K + k0 + rcol, Bl + (i * 256 + tid) * 8);
        }
        __syncthreads();

        short8 af[4], bf[4];
        #pragma unroll
        for (int t = 0; t < 4; ++t) {
            af[t] = *(const short8*)(Al + (wr * 64 + t * 16 + lm) * 32 + quad * 8);
            bf[t] = *(const short8*)(Bl + (wc * 64 + t * 16 + lm) * 32 + quad * 8);
        }
        #pragma unroll
        for (int mt = 0; mt < 4; ++mt)
            #pragma unroll
            for (int nt = 0; nt < 4; ++nt)
                acc[mt][nt] = __builtin_amdgcn_mfma_f32_16x16x32_bf16(
                    af[mt], bf[nt], acc[mt][nt], 0, 0, 0);
    }

    #pragma unroll
    for (int mt = 0; mt < 4; ++mt)
        #pragma unroll
        for (int nt = 0; nt < 4; ++nt)
            #pragma unroll
            for (int r = 0; r < 4; ++r) {
                int row = m0 + wr * 64 + mt * 16 + quad * 4 + r;
                int col = n0 + wc * 64 + nt * 16 + lm;
                storeC(&C[(size_t)row * N + col], acc[mt][nt][r]);
            }
}

// ---------------- MFMA flash attention, 4-way K-split ----------------
// Grid (S/16, NH), 256 threads = 4 waves. All waves share q rows [q0, q0+16);
// wave w processes 64-key tiles t with t % 4 == w, keeping private (m,l,O).
// Final merge through LDS. qb:[S][3072], kvb:[S][4096], kpe:[S][64],
// v16t:[NH][128][S], aout16:[S][2048].
__global__ __launch_bounds__(256) void mla_attn_kernel(
    const ushort_t* __restrict__ qb, const ushort_t* __restrict__ kvb,
    const ushort_t* __restrict__ kpe, const ushort_t* __restrict__ v16t,
    ushort_t* __restrict__ aout16)
{
    // smem: during K-loop = per-wave P tiles [4][16][72] ushort (9216 B)
    //       after K-loop  = two fp32 merge buffers [16][128] (8192 B each)
    __shared__ char smem[16384];
    __shared__ float LDSm[4][16];
    __shared__ float LDSl[4][16];
    ushort_t* Ps   = (ushort_t*)smem;
    float*    bufA = (float*)smem;
    float*    bufB = (float*)(smem + 8192);

    const int h = blockIdx.y;
    const int q0 = blockIdx.x * 16;
    const int w = threadIdx.x >> 6;
    const int lane = threadIdx.x & 63;
    const int lm = lane & 15, quad = lane >> 4;
    const ushort_t* vh = v16t + (size_t)h * D_V * S_LEN;
    ushort_t* myPs = Ps + w * 16 * 72;

    short8 qf[6];
    #pragma unroll
    for (int f = 0; f < 6; ++f)
        qf[f] = *(const short8*)(qb + (size_t)(q0 + lm) * 3072 + h * 192 + f * 32 + quad * 8);

    f32x4 O[8];
    #pragma unroll
    for (int c = 0; c < 8; ++c) O[c] = (f32x4){0.f, 0.f, 0.f, 0.f};
    float m_[4] = {-1e30f, -1e30f, -1e30f, -1e30f};
    float l_[4] = {0.f, 0.f, 0.f, 0.f};
    const float scale = 0.07216878364870322f;  // 192^-0.5
    const int kend = q0 + 16;

    for (int k0 = w * 64; k0 < kend; k0 += 256) {
        // ---- S = Q K^T for 64 keys (4 subtiles of 16) ----
        f32x4 s[4];
        #pragma unroll
        for (int st = 0; st < 4; ++st) s[st] = (f32x4){0.f, 0.f, 0.f, 0.f};
        const ushort_t* kr = kvb + (size_t)(k0 + lm) * 4096 + h * 256 + quad * 8;
        #pragma unroll
        for (int f = 0; f < 4; ++f) {
            #pragma unroll
            for (int st = 0; st < 4; ++st) {
                short8 kf = *(const short8*)(kr + (size_t)st * 16 * 4096 + f * 32);
                s[st] = __builtin_amdgcn_mfma_f32_16x16x32_bf16(qf[f], kf, s[st], 0, 0, 0);
            }
        }
        const ushort_t* pr = kpe + (size_t)(k0 + lm) * 64 + quad * 8;
        #pragma unroll
        for (int f = 0; f < 2; ++f) {
            #pragma unroll
            for (int st = 0; st < 4; ++st) {
                short8 kf = *(const short8*)(pr + (size_t)st * 16 * 64 + f * 32);
                s[st] = __builtin_amdgcn_mfma_f32_16x16x32_bf16(qf[4 + f], kf, s[st], 0, 0, 0);
            }
        }
        // ---- online softmax over 64 keys, C layout rows quad*4+r ----
        #pragma unroll
        for (int r = 0; r < 4; ++r) {
            int qrow = q0 + quad * 4 + r;
            float a[4];
            #pragma unroll
            for (int st = 0; st < 4; ++st)
                a[st] = (k0 + st * 16 + lm <= qrow) ? s[st][r] * scale : -1e30f;
            float mx = fmaxf(fmaxf(a[0], a[1]), fmaxf(a[2], a[3]));
            mx = fmaxf(mx, __shfl_xor(mx, 1));
            mx = fmaxf(mx, __shfl_xor(mx, 2));
            mx = fmaxf(mx, __shfl_xor(mx, 4));
            mx = fmaxf(mx, __shfl_xor(mx, 8));
            float mn = fmaxf(m_[r], mx);
            float p[4];
            #pragma unroll
            for (int st = 0; st < 4; ++st) p[st] = __expf(a[st] - mn);
            float alpha = __expf(m_[r] - mn);
            float ps = (p[0] + p[1]) + (p[2] + p[3]);
            ps += __shfl_xor(ps, 1);
            ps += __shfl_xor(ps, 2);
            ps += __shfl_xor(ps, 4);
            ps += __shfl_xor(ps, 8);
            l_[r] = l_[r] * alpha + ps;
            m_[r] = mn;
            #pragma unroll
            for (int c = 0; c < 8; ++c) O[c][r] *= alpha;
            #pragma unroll
            for (int st = 0; st < 4; ++st)
                myPs[(quad * 4 + r) * 72 + st * 16 + lm] = f2bf(p[st]);
        }
        // wave-local C->A layout round-trip (own buffer; no cross-wave barrier)
        asm volatile("s_waitcnt lgkmcnt(0)" ::: "memory");
        short8 pf0 = *(const short8*)(myPs + lm * 72 + quad * 8);
        short8 pf1 = *(const short8*)(myPs + lm * 72 + 32 + quad * 8);
        // ---- O += P V ----
        const ushort_t* vr = vh + (size_t)lm * S_LEN + k0 + quad * 8;
        #pragma unroll
        for (int c = 0; c < 8; ++c) {
            short8 vf0 = *(const short8*)(vr + (size_t)c * 16 * S_LEN);
            short8 vf1 = *(const short8*)(vr + (size_t)c * 16 * S_LEN + 32);
            O[c] = __builtin_amdgcn_mfma_f32_16x16x32_bf16(pf0, vf0, O[c], 0, 0, 0);
            O[c] = __builtin_amdgcn_mfma_f32_16x16x32_bf16(pf1, vf1, O[c], 0, 0, 0);
        }
    }

    // ---- merge the 4 waves' partial (m, l, O) ----
    if (lm == 0) {
        #pragma unroll
        for (int r = 0; r < 4; ++r) {
            LDSm[w][quad * 4 + r] = m_[r];
            LDSl[w][quad * 4 + r] = l_[r];
        }
    }
    __syncthreads();  // also guarantees all Ps reads are done before bufA/bufB reuse
    float Lr[4];
    #pragma unroll
    for (int r = 0; r < 4; ++r) {
        int row = quad * 4 + r;
        float M = fmaxf(fmaxf(LDSm[0][row], LDSm[1][row]),
                        fmaxf(LDSm[2][row], LDSm[3][row]));
        float L = 0.f;
        #pragma unroll
        for (int w2 = 0; w2 < 4; ++w2)
            L += __expf(LDSm[w2][row] - M) * LDSl[w2][row];
        float alpha = __expf(m_[r] - M);
        #pragma unroll
        for (int c = 0; c < 8; ++c) O[c][r] *= alpha;
        Lr[r] = L;
    }
    // Round A: wave1 -> bufA, wave3 -> bufB
    if (w == 1 || w == 3) {
        float* buf = (w == 1) ? bufA : bufB;
        #pragma unroll
        for (int c = 0; c < 8; ++c)
            #pragma unroll
            for (int r = 0; r < 4; ++r)
                buf[(quad * 4 + r) * 128 + c * 16 + lm] = O[c][r];
    }
    __syncthreads();
    if (w == 0 || w == 2) {
        float* buf = (w == 0) ? bufA : bufB;
        #pragma unroll
        for (int c = 0; c < 8; ++c)
            #pragma unroll
            for (int r = 0; r < 4; ++r)
                O[c][r] += buf[(quad * 4 + r) * 128 + c * 16 + lm];
    }
    __syncthreads();
    // Round B: wave2 -> bufA
    if (w == 2) {
        #pragma unroll
        for (int c = 0; c < 8; ++c)
            #pragma unroll
            for (int r = 0; r < 4; ++r)
                bufA[(quad * 4 + r) * 128 + c * 16 + lm] = O[c][r];
    }
    __syncthreads();
    if (w == 0) {
        #pragma unroll
        for (int c = 0; c < 8; ++c)
            #pragma unroll
            for (int r = 0; r < 4; ++r) {
                float v = O[c][r] + bufA[(quad * 4 + r) * 128 + c * 16 + lm];
                aout16[(size_t)(q0 + quad * 4 + r) * 2048 + h * D_V + c * 16 + lm] =
                    f2bf(v / Lr[r]);
            }
    }
}

extern "C" void kernel_launch(void* const* d_in, const int* in_sizes, int n_in,
                              void* d_out, int out_size, void* d_ws, size_t ws_size,
                              hipStream_t stream)
{
    (void)in_sizes; (void)n_in; (void)out_size; (void)ws_size;
    const float* hs   = (const float*)d_in[0];
    const float* Wqa  = (const float*)d_in[1];
    const float* qlnw = (const float*)d_in[2];
    const float* Wqb  = (const float*)d_in[3];
    const float* Wkva = (const float*)d_in[4];
    const float* klnw = (const float*)d_in[5];
    const float* Wkvb = (const float*)d_in[6];
    const float* Wo   = (const float*)d_in[7];
    float* out = (float*)d_out;

    ushort_t* p = (ushort_t*)d_ws;
    ushort_t* hs16   = p; p += (size_t)S_LEN * H_DIM;
    ushort_t* WqaT   = p; p += (size_t)Q_LORA * H_DIM;
    ushort_t* WqbT   = p; p += (size_t)3072 * Q_LORA;
    ushort_t* WkvaT  = p; p += (size_t)640 * H_DIM;
    ushort_t* WkvbT  = p; p += (size_t)4096 * KV_LORA;
    ushort_t* WoT    = p; p += (size_t)H_DIM * H_DIM;
    ushort_t* qa16r  = p; p += (size_t)S_LEN * Q_LORA;
    ushort_t* qa16   = p; p += (size_t)S_LEN * Q_LORA;
    ushort_t* qbuf16 = p; p += (size_t)S_LEN * 3072;
    ushort_t* ckv16r = p; p += (size_t)S_LEN * 640;
    ushort_t* ckv16n = p; p += (size_t)S_LEN * KV_LORA;
    ushort_t* kpe16  = p; p += (size_t)S_LEN * D_ROPE;
    ushort_t* kv16   = p; p += (size_t)S_LEN * 4096;
    ushort_t* v16t   = p; p += (size_t)NH * D_V * S_LEN;
    ushort_t* aout16 = p; p += (size_t)S_LEN * 2048;

    // 0. conversions
    conv_f32_bf16<<<(S_LEN * H_DIM / 4 + 255) / 256, 256, 0, stream>>>(hs, hs16, S_LEN * H_DIM);
    convT_kernel<<<dim3(Q_LORA / 32, H_DIM / 32), 256, 0, stream>>>(Wqa, WqaT, H_DIM, Q_LORA);
    convT_kernel<<<dim3(3072 / 32, Q_LORA / 32), 256, 0, stream>>>(Wqb, WqbT, Q_LORA, 3072);
    convT_kernel<<<dim3(640 / 32, H_DIM / 32), 256, 0, stream>>>(Wkva, WkvaT, H_DIM, 576);
    convT_kernel<<<dim3(4096 / 32, KV_LORA / 32), 256, 0, stream>>>(Wkvb, WkvbT, KV_LORA, 4096);
    convT_kernel<<<dim3(H_DIM / 32, H_DIM / 32), 256, 0, stream>>>(Wo, WoT, H_DIM, H_DIM);

    // 1. qa16r = hs16 @ WqaT^T   [2048 x 1536, K=2048]
    mfma_gemm_bt<ushort_t><<<dim3(Q_LORA / 128, S_LEN / 128), 256, 0, stream>>>(
        hs16, WqaT, qa16r, Q_LORA, H_DIM);
    // 2. rmsnorm
    rmsnorm_bf16_kernel<<<S_LEN, 256, 0, stream>>>(qa16r, Q_LORA, qa16, Q_LORA, Q_LORA, qlnw);
    // 3. qbuf16 = qa16 @ WqbT^T  [2048 x 3072, K=1536]
    mfma_gemm_bt<ushort_t><<<dim3(3072 / 128, S_LEN / 128), 256, 0, stream>>>(
        qa16, WqbT, qbuf16, 3072, Q_LORA);
    // 4. ckv16r = hs16 @ WkvaT^T [2048 x 640, K=2048]
    mfma_gemm_bt<ushort_t><<<dim3(640 / 128, S_LEN / 128), 256, 0, stream>>>(
        hs16, WkvaT, ckv16r, 640, H_DIM);
    // 5. rmsnorm ckv (cols 0..512, stride 640 -> packed 512)
    rmsnorm_bf16_kernel<<<S_LEN, 256, 0, stream>>>(ckv16r, 640, ckv16n, KV_LORA, KV_LORA, klnw);
    // 6. RoPE: q (in place on qbuf16) and k (ckv16r cols 512.. -> kpe16)
    rope_bf16_kernel<<<(S_LEN * NH * 32 + 255) / 256, 256, 0, stream>>>(
        qbuf16, 3072, D_NOPE, qbuf16, 3072, D_NOPE, D_QK, NH);
    rope_bf16_kernel<<<(S_LEN * 32 + 255) / 256, 256, 0, stream>>>(
        ckv16r, 640, KV_LORA, kpe16, D_ROPE, 0, 0, 1);
    // 7. kv16 = ckv16n @ WkvbT^T [2048 x 4096, K=512]
    mfma_gemm_bt<ushort_t><<<dim3(4096 / 128, S_LEN / 128), 256, 0, stream>>>(
        ckv16n, WkvbT, kv16, 4096, KV_LORA);
    // 8. V transpose
    conv_vT_kernel<<<dim3(S_LEN / 32, D_V / 32, NH), 256, 0, stream>>>(kv16, v16t);
    // 9. attention (4-way K-split)
    mla_attn_kernel<<<dim3(S_LEN / 16, NH), 256, 0, stream>>>(qbuf16, kv16, kpe16, v16t, aout16);
    // 10. out = aout16 @ WoT^T [2048 x 2048, K=2048], fp32 store
    mfma_gemm_bt<float><<<dim3(H_DIM / 128, S_LEN / 128), 256, 0, stream>>>(
        aout16, WoT, out, H_DIM, H_DIM);
}

// Round 6
// 444.332 us; speedup vs baseline: 7.5929x; 1.3282x over previous
//
#include <hip/hip_runtime.h>
#include <hip/hip_bf16.h>
#include <math.h>

#define S_LEN 2048
#define H_DIM 2048
#define NH 16
#define Q_LORA 1536
#define KV_LORA 512
#define D_NOPE 128
#define D_ROPE 64
#define D_V 128
#define D_QK 192

typedef unsigned short ushort_t;
typedef __attribute__((ext_vector_type(8))) short short8;
typedef __attribute__((ext_vector_type(4))) float f32x4;

__device__ __forceinline__ ushort_t f2bf(float f) {
    unsigned int u = __float_as_uint(f);
    u = (u + 0x7FFFu + ((u >> 16) & 1u)) >> 16;
    return (ushort_t)u;
}
__device__ __forceinline__ float bf2f(ushort_t u) {
    return __uint_as_float(((unsigned int)u) << 16);
}

__device__ __forceinline__ void storeC(float* p, float v) { *p = v; }
__device__ __forceinline__ void storeC(ushort_t* p, float v) { *p = f2bf(v); }

__device__ __forceinline__ void gload_lds16(const ushort_t* g, ushort_t* l) {
    __builtin_amdgcn_global_load_lds(
        (const __attribute__((address_space(1))) unsigned int*)(const void*)g,
        (__attribute__((address_space(3))) unsigned int*)(void*)l, 16, 0, 0);
}

// ---------------- fp32 -> bf16 elementwise (n % 4 == 0) ----------------
__global__ __launch_bounds__(256) void conv_f32_bf16(
    const float* __restrict__ X, ushort_t* __restrict__ Y, int n)
{
    int base = (blockIdx.x * 256 + threadIdx.x) * 4;
    if (base >= n) return;
    float4 v = *(const float4*)(X + base);
    Y[base + 0] = f2bf(v.x);
    Y[base + 1] = f2bf(v.y);
    Y[base + 2] = f2bf(v.z);
    Y[base + 3] = f2bf(v.w);
}

// ------------- weight transpose+convert: W[K][N] f32 -> Wt[Npad][K] bf16 -------------
__global__ __launch_bounds__(256) void convT_kernel(
    const float* __restrict__ W, ushort_t* __restrict__ Wt, int K, int N)
{
    __shared__ float tile[32][33];
    const int k0 = blockIdx.y * 32, n0 = blockIdx.x * 32;
    const int tr = threadIdx.x >> 5, tc = threadIdx.x & 31;
    #pragma unroll
    for (int i = 0; i < 4; ++i) {
        int r = tr + i * 8;
        float v = 0.f;
        if (n0 + tc < N) v = W[(size_t)(k0 + r) * N + n0 + tc];
        tile[r][tc] = v;
    }
    __syncthreads();
    #pragma unroll
    for (int i = 0; i < 4; ++i) {
        int r = tr + i * 8;  // n-index within tile
        Wt[(size_t)(n0 + r) * K + k0 + tc] = f2bf(tile[tc][r]);
    }
}

// ---------------- bf16 rmsnorm ----------------
__global__ __launch_bounds__(256) void rmsnorm_bf16_kernel(
    const ushort_t* __restrict__ X, int inStride,
    ushort_t* __restrict__ Y, int outStride, int K, const float* __restrict__ w)
{
    __shared__ float red[4];
    const ushort_t* x = X + (size_t)blockIdx.x * inStride;
    ushort_t* y = Y + (size_t)blockIdx.x * outStride;
    float ss = 0.f;
    for (int i = threadIdx.x; i < K; i += 256) { float v = bf2f(x[i]); ss += v * v; }
    #pragma unroll
    for (int off = 32; off > 0; off >>= 1) ss += __shfl_down(ss, off);
    int lane = threadIdx.x & 63, wid = threadIdx.x >> 6;
    if (lane == 0) red[wid] = ss;
    __syncthreads();
    float tot = red[0] + red[1] + red[2] + red[3];
    float rs = rsqrtf(tot / (float)K + 1e-6f);
    for (int i = threadIdx.x; i < K; i += 256)
        y[i] = f2bf(bf2f(x[i]) * rs * w[i]);
}

// ---------------- bf16 RoPE ----------------
__global__ void rope_bf16_kernel(
    const ushort_t* __restrict__ src, int srcStride, int srcOff,
    ushort_t* __restrict__ dst, int dstStride, int dstOff,
    int headStride, int nHeads)
{
    int idx = blockIdx.x * 256 + threadIdx.x;
    if (idx >= S_LEN * nHeads * 32) return;
    int i = idx & 31;
    int sh = idx >> 5;
    int hh = sh % nHeads;
    int s = sh / nHeads;
    float inv = powf(10000.0f, -(2.0f * i) / 64.0f);
    float ang = (float)s * inv;
    float c = cosf(ang), sn = sinf(ang);
    const ushort_t* p = src + (size_t)s * srcStride + hh * headStride + srcOff;
    ushort_t* q = dst + (size_t)s * dstStride + hh * headStride + dstOff;
    float x1 = bf2f(p[i]), x2 = bf2f(p[i + 32]);
    q[i]      = f2bf(x1 * c - x2 * sn);
    q[i + 32] = f2bf(x2 * c + x1 * sn);
}

// ---------------- V transpose: kv16[s][h*256+128+dv] -> v16t[h][dv][s] ----------------
__global__ __launch_bounds__(256) void conv_vT_kernel(
    const ushort_t* __restrict__ kv, ushort_t* __restrict__ v16t)
{
    __shared__ ushort_t tile[32][33];
    const int h = blockIdx.z;
    const int s0 = blockIdx.x * 32, d0 = blockIdx.y * 32;
    const int tr = threadIdx.x >> 5, tc = threadIdx.x & 31;
    #pragma unroll
    for (int i = 0; i < 4; ++i) {
        int r = tr + i * 8;  // s
        tile[r][tc] = kv[(size_t)(s0 + r) * 4096 + h * 256 + D_NOPE + d0 + tc];
    }
    __syncthreads();
    #pragma unroll
    for (int i = 0; i < 4; ++i) {
        int r = tr + i * 8;  // dv
        v16t[(size_t)h * D_V * S_LEN + (size_t)(d0 + r) * S_LEN + s0 + tc] = tile[tc][r];
    }
}

// ---------------- m97-style MFMA GEMM: C[M][N] = A[M][K] * Bt[N][K]^T ----------------
template <typename CT>
__global__ __launch_bounds__(256) void mfma_gemm_bt(
    const ushort_t* __restrict__ A, const ushort_t* __restrict__ Bt,
    CT* __restrict__ C, int N, int K)
{
    __shared__ ushort_t Al[128 * 32];
    __shared__ ushort_t Bl[128 * 32];
    const int m0 = blockIdx.y * 128, n0 = blockIdx.x * 128;
    const int tid = threadIdx.x;
    const int lane = tid & 63;
    const int w = tid >> 6;
    const int lm = lane & 15, quad = lane >> 4;
    const int wr = w >> 1, wc = w & 1;

    f32x4 acc[4][4];
    #pragma unroll
    for (int a = 0; a < 4; ++a)
        #pragma unroll
        for (int b = 0; b < 4; ++b) acc[a][b] = (f32x4){0.f, 0.f, 0.f, 0.f};

    const int rrow = tid >> 2;
    const int rcol = (tid & 3) * 8;

    for (int k0 = 0; k0 < K; k0 += 32) {
        __syncthreads();
        #pragma unroll
        for (int i = 0; i < 2; ++i) {
            int row = i * 64 + rrow;
            gload_lds16(A  + (size_t)(m0 + row) * K + k0 + rcol, Al + (i * 256 + tid) * 8);
            gload_lds16(Bt + (size_t)(n0 + row) * K + k0 + rcol, Bl + (i * 256 + tid) * 8);
        }
        __syncthreads();

        short8 af[4], bf[4];
        #pragma unroll
        for (int t = 0; t < 4; ++t) {
            af[t] = *(const short8*)(Al + (wr * 64 + t * 16 + lm) * 32 + quad * 8);
            bf[t] = *(const short8*)(Bl + (wc * 64 + t * 16 + lm) * 32 + quad * 8);
        }
        #pragma unroll
        for (int mt = 0; mt < 4; ++mt)
            #pragma unroll
            for (int nt = 0; nt < 4; ++nt)
                acc[mt][nt] = __builtin_amdgcn_mfma_f32_16x16x32_bf16(
                    af[mt], bf[nt], acc[mt][nt], 0, 0, 0);
    }

    #pragma unroll
    for (int mt = 0; mt < 4; ++mt)
        #pragma unroll
        for (int nt = 0; nt < 4; ++nt)
            #pragma unroll
            for (int r = 0; r < 4; ++r) {
                int row = m0 + wr * 64 + mt * 16 + quad * 4 + r;
                int col = n0 + wc * 64 + nt * 16 + lm;
                storeC(&C[(size_t)row * N + col], acc[mt][nt][r]);
            }
}

// ---------------- MFMA flash attention, LDS-staged K/V ----------------
// Grid (NH, S/64) with q0 DESCENDING (heavy blocks first). 256 threads = 4 waves;
// wave w owns q rows [q0+16w, q0+16w+16). Per 64-key tile the block cooperatively
// stages K-nope, K-rope, V^T into LDS (global_load_lds, wave-linear chunk-major
// layout [chunk][key][32] -> fragment ds_read_b128 at 64B row stride, conflict-free).
// qb:[S][3072], kvb:[S][4096], kpe:[S][64], v16t:[NH][128][S], aout16:[S][2048].
__global__ __launch_bounds__(256) void mla_attn_kernel(
    const ushort_t* __restrict__ qb, const ushort_t* __restrict__ kvb,
    const ushort_t* __restrict__ kpe, const ushort_t* __restrict__ v16t,
    ushort_t* __restrict__ aout16)
{
    __shared__ ushort_t Kn[4 * 64 * 32];   // [f 0..3][key 0..63][32]  16 KB
    __shared__ ushort_t Kr[2 * 64 * 32];   // [f2 0..1][key][32]        8 KB
    __shared__ ushort_t Vt[2 * 128 * 32];  // [half 0..1][dv 0..127][32] 16 KB
    __shared__ ushort_t Ps[4][16][72];     // per-wave P [q16][key64]    9 KB

    const int h = blockIdx.x;
    const int q0 = S_LEN - 64 - blockIdx.y * 64;  // heavy-first
    const int tid = threadIdx.x;
    const int w = tid >> 6;
    const int lane = tid & 63;
    const int lm = lane & 15, quad = lane >> 4;
    const int qw = q0 + w * 16;
    ushort_t* myPs = &Ps[w][0][0];

    // Q fragments: A[m=lm][k=quad*8+j], 6 chunks of 32 over D_QK=192
    short8 qf[6];
    #pragma unroll
    for (int f = 0; f < 6; ++f)
        qf[f] = *(const short8*)(qb + (size_t)(qw + lm) * 3072 + h * 192 + f * 32 + quad * 8);

    f32x4 O[8];
    #pragma unroll
    for (int c = 0; c < 8; ++c) O[c] = (f32x4){0.f, 0.f, 0.f, 0.f};
    float m_[4] = {-1e30f, -1e30f, -1e30f, -1e30f};
    float l_[4] = {0.f, 0.f, 0.f, 0.f};
    const float scale = 0.07216878364870322f;  // 192^-0.5

    // staging lane decomposition (16 keys x 2 16B-pieces per 32-chunk)
    const int skey = lane >> 2;        // 0..15 key-within-16
    const int ssub = (lane & 3) * 8;   // 0/8/16/24 ushort offset within chunk

    const int kend = q0 + 64;
    for (int k0 = 0; k0 < kend; k0 += 64) {
        __syncthreads();  // previous tile's LDS reads complete
        {
            // K-nope: 16 instr (f=w, i=0..3): Kn[f][i*16+skey][ssub..+7]
            #pragma unroll
            for (int i = 0; i < 4; ++i)
                gload_lds16(kvb + (size_t)(k0 + i * 16 + skey) * 4096 + h * 256 + w * 32 + ssub,
                            Kn + w * 2048 + i * 512 + lane * 8);
            // K-rope: 8 instr (f2=w>>1, i=(w&1)*2..+1)
            #pragma unroll
            for (int i = 0; i < 2; ++i) {
                int ii = (w & 1) * 2 + i;
                gload_lds16(kpe + (size_t)(k0 + ii * 16 + skey) * 64 + (w >> 1) * 32 + ssub,
                            Kr + (w >> 1) * 2048 + ii * 512 + lane * 8);
            }
            // V^T: 16 instr (half=w>>1, j=(w&1)*4..+3): Vt[half][j*16+skey(dv)][ssub]
            #pragma unroll
            for (int j = 0; j < 4; ++j) {
                int jj = (w & 1) * 4 + j;
                gload_lds16(v16t + ((size_t)h * 128 + jj * 16 + skey) * S_LEN + k0 + (w >> 1) * 32 + ssub,
                            Vt + (w >> 1) * 4096 + jj * 512 + lane * 8);
            }
        }
        __syncthreads();  // staging visible

        if (k0 < qw + 16) {  // wave-uniform causal skip
            // ---- S = Q K^T (4 key-subtiles of 16) ----
            f32x4 s[4];
            #pragma unroll
            for (int st = 0; st < 4; ++st) s[st] = (f32x4){0.f, 0.f, 0.f, 0.f};
            #pragma unroll
            for (int f = 0; f < 4; ++f)
                #pragma unroll
                for (int st = 0; st < 4; ++st) {
                    short8 kf = *(const short8*)(Kn + f * 2048 + (st * 16 + lm) * 32 + quad * 8);
                    s[st] = __builtin_amdgcn_mfma_f32_16x16x32_bf16(qf[f], kf, s[st], 0, 0, 0);
                }
            #pragma unroll
            for (int f2 = 0; f2 < 2; ++f2)
                #pragma unroll
                for (int st = 0; st < 4; ++st) {
                    short8 kf = *(const short8*)(Kr + f2 * 2048 + (st * 16 + lm) * 32 + quad * 8);
                    s[st] = __builtin_amdgcn_mfma_f32_16x16x32_bf16(qf[4 + f2], kf, s[st], 0, 0, 0);
                }
            // ---- online softmax, C layout rows quad*4+r ----
            #pragma unroll
            for (int r = 0; r < 4; ++r) {
                int qrow = qw + quad * 4 + r;
                float a[4];
                #pragma unroll
                for (int st = 0; st < 4; ++st)
                    a[st] = (k0 + st * 16 + lm <= qrow) ? s[st][r] * scale : -1e30f;
                float mx = fmaxf(fmaxf(a[0], a[1]), fmaxf(a[2], a[3]));
                mx = fmaxf(mx, __shfl_xor(mx, 1));
                mx = fmaxf(mx, __shfl_xor(mx, 2));
                mx = fmaxf(mx, __shfl_xor(mx, 4));
                mx = fmaxf(mx, __shfl_xor(mx, 8));
                float mn = fmaxf(m_[r], mx);
                float p[4];
                #pragma unroll
                for (int st = 0; st < 4; ++st) p[st] = __expf(a[st] - mn);
                float alpha = __expf(m_[r] - mn);
                float ps = (p[0] + p[1]) + (p[2] + p[3]);
                ps += __shfl_xor(ps, 1);
                ps += __shfl_xor(ps, 2);
                ps += __shfl_xor(ps, 4);
                ps += __shfl_xor(ps, 8);
                l_[r] = l_[r] * alpha + ps;
                m_[r] = mn;
                #pragma unroll
                for (int c = 0; c < 8; ++c) O[c][r] *= alpha;
                #pragma unroll
                for (int st = 0; st < 4; ++st)
                    myPs[(quad * 4 + r) * 72 + st * 16 + lm] = f2bf(p[st]);
            }
            // wave-local C->A round-trip (own Ps buffer)
            asm volatile("s_waitcnt lgkmcnt(0)" ::: "memory");
            short8 pf0 = *(const short8*)(myPs + lm * 72 + quad * 8);
            short8 pf1 = *(const short8*)(myPs + lm * 72 + 32 + quad * 8);
            // ---- O += P V ----
            #pragma unroll
            for (int c = 0; c < 8; ++c) {
                short8 vf0 = *(const short8*)(Vt + (c * 16 + lm) * 32 + quad * 8);
                short8 vf1 = *(const short8*)(Vt + 4096 + (c * 16 + lm) * 32 + quad * 8);
                O[c] = __builtin_amdgcn_mfma_f32_16x16x32_bf16(pf0, vf0, O[c], 0, 0, 0);
                O[c] = __builtin_amdgcn_mfma_f32_16x16x32_bf16(pf1, vf1, O[c], 0, 0, 0);
            }
        }
    }
    // epilogue
    #pragma unroll
    for (int c = 0; c < 8; ++c)
        #pragma unroll
        for (int r = 0; r < 4; ++r) {
            int qrow = qw + quad * 4 + r;
            aout16[(size_t)qrow * 2048 + h * D_V + c * 16 + lm] = f2bf(O[c][r] / l_[r]);
        }
}

extern "C" void kernel_launch(void* const* d_in, const int* in_sizes, int n_in,
                              void* d_out, int out_size, void* d_ws, size_t ws_size,
                              hipStream_t stream)
{
    (void)in_sizes; (void)n_in; (void)out_size; (void)ws_size;
    const float* hs   = (const float*)d_in[0];
    const float* Wqa  = (const float*)d_in[1];
    const float* qlnw = (const float*)d_in[2];
    const float* Wqb  = (const float*)d_in[3];
    const float* Wkva = (const float*)d_in[4];
    const float* klnw = (const float*)d_in[5];
    const float* Wkvb = (const float*)d_in[6];
    const float* Wo   = (const float*)d_in[7];
    float* out = (float*)d_out;

    ushort_t* p = (ushort_t*)d_ws;
    ushort_t* hs16   = p; p += (size_t)S_LEN * H_DIM;
    ushort_t* WqaT   = p; p += (size_t)Q_LORA * H_DIM;
    ushort_t* WqbT   = p; p += (size_t)3072 * Q_LORA;
    ushort_t* WkvaT  = p; p += (size_t)640 * H_DIM;
    ushort_t* WkvbT  = p; p += (size_t)4096 * KV_LORA;
    ushort_t* WoT    = p; p += (size_t)H_DIM * H_DIM;
    ushort_t* qa16r  = p; p += (size_t)S_LEN * Q_LORA;
    ushort_t* qa16   = p; p += (size_t)S_LEN * Q_LORA;
    ushort_t* qbuf16 = p; p += (size_t)S_LEN * 3072;
    ushort_t* ckv16r = p; p += (size_t)S_LEN * 640;
    ushort_t* ckv16n = p; p += (size_t)S_LEN * KV_LORA;
    ushort_t* kpe16  = p; p += (size_t)S_LEN * D_ROPE;
    ushort_t* kv16   = p; p += (size_t)S_LEN * 4096;
    ushort_t* v16t   = p; p += (size_t)NH * D_V * S_LEN;
    ushort_t* aout16 = p; p += (size_t)S_LEN * 2048;

    // 0. conversions
    conv_f32_bf16<<<(S_LEN * H_DIM / 4 + 255) / 256, 256, 0, stream>>>(hs, hs16, S_LEN * H_DIM);
    convT_kernel<<<dim3(Q_LORA / 32, H_DIM / 32), 256, 0, stream>>>(Wqa, WqaT, H_DIM, Q_LORA);
    convT_kernel<<<dim3(3072 / 32, Q_LORA / 32), 256, 0, stream>>>(Wqb, WqbT, Q_LORA, 3072);
    convT_kernel<<<dim3(640 / 32, H_DIM / 32), 256, 0, stream>>>(Wkva, WkvaT, H_DIM, 576);
    convT_kernel<<<dim3(4096 / 32, KV_LORA / 32), 256, 0, stream>>>(Wkvb, WkvbT, KV_LORA, 4096);
    convT_kernel<<<dim3(H_DIM / 32, H_DIM / 32), 256, 0, stream>>>(Wo, WoT, H_DIM, H_DIM);

    // 1. qa16r = hs16 @ WqaT^T   [2048 x 1536, K=2048]
    mfma_gemm_bt<ushort_t><<<dim3(Q_LORA / 128, S_LEN / 128), 256, 0, stream>>>(
        hs16, WqaT, qa16r, Q_LORA, H_DIM);
    // 2. rmsnorm
    rmsnorm_bf16_kernel<<<S_LEN, 256, 0, stream>>>(qa16r, Q_LORA, qa16, Q_LORA, Q_LORA, qlnw);
    // 3. qbuf16 = qa16 @ WqbT^T  [2048 x 3072, K=1536]
    mfma_gemm_bt<ushort_t><<<dim3(3072 / 128, S_LEN / 128), 256, 0, stream>>>(
        qa16, WqbT, qbuf16, 3072, Q_LORA);
    // 4. ckv16r = hs16 @ WkvaT^T [2048 x 640, K=2048]
    mfma_gemm_bt<ushort_t><<<dim3(640 / 128, S_LEN / 128), 256, 0, stream>>>(
        hs16, WkvaT, ckv16r, 640, H_DIM);
    // 5. rmsnorm ckv (cols 0..512, stride 640 -> packed 512)
    rmsnorm_bf16_kernel<<<S_LEN, 256, 0, stream>>>(ckv16r, 640, ckv16n, KV_LORA, KV_LORA, klnw);
    // 6. RoPE: q (in place on qbuf16) and k (ckv16r cols 512.. -> kpe16)
    rope_bf16_kernel<<<(S_LEN * NH * 32 + 255) / 256, 256, 0, stream>>>(
        qbuf16, 3072, D_NOPE, qbuf16, 3072, D_NOPE, D_QK, NH);
    rope_bf16_kernel<<<(S_LEN * 32 + 255) / 256, 256, 0, stream>>>(
        ckv16r, 640, KV_LORA, kpe16, D_ROPE, 0, 0, 1);
    // 7. kv16 = ckv16n @ WkvbT^T [2048 x 4096, K=512]
    mfma_gemm_bt<ushort_t><<<dim3(4096 / 128, S_LEN / 128), 256, 0, stream>>>(
        ckv16n, WkvbT, kv16, 4096, KV_LORA);
    // 8. V transpose
    conv_vT_kernel<<<dim3(S_LEN / 32, D_V / 32, NH), 256, 0, stream>>>(kv16, v16t);
    // 9. attention (block-cooperative LDS staging, heavy-first)
    mla_attn_kernel<<<dim3(NH, S_LEN / 64), 256, 0, stream>>>(qbuf16, kv16, kpe16, v16t, aout16);
    // 10. out = aout16 @ WoT^T [2048 x 2048, K=2048], fp32 store
    mfma_gemm_bt<float><<<dim3(H_DIM / 128, S_LEN / 128), 256, 0, stream>>>(
        aout16, WoT, out, H_DIM, H_DIM);
}

// Round 7
// 419.798 us; speedup vs baseline: 8.0366x; 1.0584x over previous
//
#include <hip/hip_runtime.h>
#include <hip/hip_bf16.h>
#include <math.h>

#define S_LEN 2048
#define H_DIM 2048
#define NH 16
#define Q_LORA 1536
#define KV_LORA 512
#define D_NOPE 128
#define D_ROPE 64
#define D_V 128
#define D_QK 192

typedef unsigned short ushort_t;
typedef __attribute__((ext_vector_type(8))) short short8;
typedef __attribute__((ext_vector_type(4))) float f32x4;

__device__ __forceinline__ ushort_t f2bf(float f) {
    unsigned int u = __float_as_uint(f);
    u = (u + 0x7FFFu + ((u >> 16) & 1u)) >> 16;
    return (ushort_t)u;
}
__device__ __forceinline__ float bf2f(ushort_t u) {
    return __uint_as_float(((unsigned int)u) << 16);
}

__device__ __forceinline__ void storeC(float* p, float v) { *p = v; }
__device__ __forceinline__ void storeC(ushort_t* p, float v) { *p = f2bf(v); }

__device__ __forceinline__ void gload_lds16(const ushort_t* g, ushort_t* l) {
    __builtin_amdgcn_global_load_lds(
        (const __attribute__((address_space(1))) unsigned int*)(const void*)g,
        (__attribute__((address_space(3))) unsigned int*)(void*)l, 16, 0, 0);
}

// ---------------- fp32 -> bf16 elementwise (n % 4 == 0) ----------------
__global__ __launch_bounds__(256) void conv_f32_bf16(
    const float* __restrict__ X, ushort_t* __restrict__ Y, int n)
{
    int base = (blockIdx.x * 256 + threadIdx.x) * 4;
    if (base >= n) return;
    float4 v = *(const float4*)(X + base);
    Y[base + 0] = f2bf(v.x);
    Y[base + 1] = f2bf(v.y);
    Y[base + 2] = f2bf(v.z);
    Y[base + 3] = f2bf(v.w);
}

// ------------- weight transpose+convert: W[K][N] f32 -> Wt[Npad][K] bf16 -------------
__global__ __launch_bounds__(256) void convT_kernel(
    const float* __restrict__ W, ushort_t* __restrict__ Wt, int K, int N)
{
    __shared__ float tile[32][33];
    const int k0 = blockIdx.y * 32, n0 = blockIdx.x * 32;
    const int tr = threadIdx.x >> 5, tc = threadIdx.x & 31;
    #pragma unroll
    for (int i = 0; i < 4; ++i) {
        int r = tr + i * 8;
        float v = 0.f;
        if (n0 + tc < N) v = W[(size_t)(k0 + r) * N + n0 + tc];
        tile[r][tc] = v;
    }
    __syncthreads();
    #pragma unroll
    for (int i = 0; i < 4; ++i) {
        int r = tr + i * 8;  // n-index within tile
        Wt[(size_t)(n0 + r) * K + k0 + tc] = f2bf(tile[tc][r]);
    }
}

// ---------------- bf16 rmsnorm ----------------
__global__ __launch_bounds__(256) void rmsnorm_bf16_kernel(
    const ushort_t* __restrict__ X, int inStride,
    ushort_t* __restrict__ Y, int outStride, int K, const float* __restrict__ w)
{
    __shared__ float red[4];
    const ushort_t* x = X + (size_t)blockIdx.x * inStride;
    ushort_t* y = Y + (size_t)blockIdx.x * outStride;
    float ss = 0.f;
    for (int i = threadIdx.x; i < K; i += 256) { float v = bf2f(x[i]); ss += v * v; }
    #pragma unroll
    for (int off = 32; off > 0; off >>= 1) ss += __shfl_down(ss, off);
    int lane = threadIdx.x & 63, wid = threadIdx.x >> 6;
    if (lane == 0) red[wid] = ss;
    __syncthreads();
    float tot = red[0] + red[1] + red[2] + red[3];
    float rs = rsqrtf(tot / (float)K + 1e-6f);
    for (int i = threadIdx.x; i < K; i += 256)
        y[i] = f2bf(bf2f(x[i]) * rs * w[i]);
}

// ---------------- bf16 RoPE ----------------
__global__ void rope_bf16_kernel(
    const ushort_t* __restrict__ src, int srcStride, int srcOff,
    ushort_t* __restrict__ dst, int dstStride, int dstOff,
    int headStride, int nHeads)
{
    int idx = blockIdx.x * 256 + threadIdx.x;
    if (idx >= S_LEN * nHeads * 32) return;
    int i = idx & 31;
    int sh = idx >> 5;
    int hh = sh % nHeads;
    int s = sh / nHeads;
    float inv = powf(10000.0f, -(2.0f * i) / 64.0f);
    float ang = (float)s * inv;
    float c = cosf(ang), sn = sinf(ang);
    const ushort_t* p = src + (size_t)s * srcStride + hh * headStride + srcOff;
    ushort_t* q = dst + (size_t)s * dstStride + hh * headStride + dstOff;
    float x1 = bf2f(p[i]), x2 = bf2f(p[i + 32]);
    q[i]      = f2bf(x1 * c - x2 * sn);
    q[i + 32] = f2bf(x2 * c + x1 * sn);
}

// ---------------- V transpose: kv16[s][h*256+128+dv] -> v16t[h][dv][s] ----------------
__global__ __launch_bounds__(256) void conv_vT_kernel(
    const ushort_t* __restrict__ kv, ushort_t* __restrict__ v16t)
{
    __shared__ ushort_t tile[32][33];
    const int h = blockIdx.z;
    const int s0 = blockIdx.x * 32, d0 = blockIdx.y * 32;
    const int tr = threadIdx.x >> 5, tc = threadIdx.x & 31;
    #pragma unroll
    for (int i = 0; i < 4; ++i) {
        int r = tr + i * 8;  // s
        tile[r][tc] = kv[(size_t)(s0 + r) * 4096 + h * 256 + D_NOPE + d0 + tc];
    }
    __syncthreads();
    #pragma unroll
    for (int i = 0; i < 4; ++i) {
        int r = tr + i * 8;  // dv
        v16t[(size_t)h * D_V * S_LEN + (size_t)(d0 + r) * S_LEN + s0 + tc] = tile[tc][r];
    }
}

// ---------------- m97-style MFMA GEMM: C[M][N] = A[M][K] * Bt[N][K]^T ----------------
template <typename CT>
__global__ __launch_bounds__(256) void mfma_gemm_bt(
    const ushort_t* __restrict__ A, const ushort_t* __restrict__ Bt,
    CT* __restrict__ C, int N, int K)
{
    __shared__ ushort_t Al[128 * 32];
    __shared__ ushort_t Bl[128 * 32];
    const int m0 = blockIdx.y * 128, n0 = blockIdx.x * 128;
    const int tid = threadIdx.x;
    const int lane = tid & 63;
    const int w = tid >> 6;
    const int lm = lane & 15, quad = lane >> 4;
    const int wr = w >> 1, wc = w & 1;

    f32x4 acc[4][4];
    #pragma unroll
    for (int a = 0; a < 4; ++a)
        #pragma unroll
        for (int b = 0; b < 4; ++b) acc[a][b] = (f32x4){0.f, 0.f, 0.f, 0.f};

    const int rrow = tid >> 2;
    const int rcol = (tid & 3) * 8;

    for (int k0 = 0; k0 < K; k0 += 32) {
        __syncthreads();
        #pragma unroll
        for (int i = 0; i < 2; ++i) {
            int row = i * 64 + rrow;
            gload_lds16(A  + (size_t)(m0 + row) * K + k0 + rcol, Al + (i * 256 + tid) * 8);
            gload_lds16(Bt + (size_t)(n0 + row) * K + k0 + rcol, Bl + (i * 256 + tid) * 8);
        }
        __syncthreads();

        short8 af[4], bf[4];
        #pragma unroll
        for (int t = 0; t < 4; ++t) {
            af[t] = *(const short8*)(Al + (wr * 64 + t * 16 + lm) * 32 + quad * 8);
            bf[t] = *(const short8*)(Bl + (wc * 64 + t * 16 + lm) * 32 + quad * 8);
        }
        #pragma unroll
        for (int mt = 0; mt < 4; ++mt)
            #pragma unroll
            for (int nt = 0; nt < 4; ++nt)
                acc[mt][nt] = __builtin_amdgcn_mfma_f32_16x16x32_bf16(
                    af[mt], bf[nt], acc[mt][nt], 0, 0, 0);
    }

    #pragma unroll
    for (int mt = 0; mt < 4; ++mt)
        #pragma unroll
        for (int nt = 0; nt < 4; ++nt)
            #pragma unroll
            for (int r = 0; r < 4; ++r) {
                int row = m0 + wr * 64 + mt * 16 + quad * 4 + r;
                int col = n0 + wc * 64 + nt * 16 + lm;
                storeC(&C[(size_t)row * N + col], acc[mt][nt][r]);
            }
}

// online-softmax update for one 16x64 score tile in C layout; writes P (bf16) to ps[16][72]
__device__ __forceinline__ void softmax_step(
    f32x4 s[4], int k0, int qw, int lm, int quad,
    float m_[4], float l_[4], f32x4 O[8], ushort_t* ps)
{
    const float scale = 0.07216878364870322f;  // 192^-0.5
    #pragma unroll
    for (int r = 0; r < 4; ++r) {
        int qrow = qw + quad * 4 + r;
        float a[4];
        #pragma unroll
        for (int st = 0; st < 4; ++st)
            a[st] = (k0 + st * 16 + lm <= qrow) ? s[st][r] * scale : -1e30f;
        float mx = fmaxf(fmaxf(a[0], a[1]), fmaxf(a[2], a[3]));
        mx = fmaxf(mx, __shfl_xor(mx, 1));
        mx = fmaxf(mx, __shfl_xor(mx, 2));
        mx = fmaxf(mx, __shfl_xor(mx, 4));
        mx = fmaxf(mx, __shfl_xor(mx, 8));
        float mn = fmaxf(m_[r], mx);
        float p[4];
        #pragma unroll
        for (int st = 0; st < 4; ++st) p[st] = __expf(a[st] - mn);
        float alpha = __expf(m_[r] - mn);
        float psum = (p[0] + p[1]) + (p[2] + p[3]);
        psum += __shfl_xor(psum, 1);
        psum += __shfl_xor(psum, 2);
        psum += __shfl_xor(psum, 4);
        psum += __shfl_xor(psum, 8);
        l_[r] = l_[r] * alpha + psum;
        m_[r] = mn;
        #pragma unroll
        for (int c = 0; c < 8; ++c) O[c][r] *= alpha;
        #pragma unroll
        for (int st = 0; st < 4; ++st)
            ps[(quad * 4 + r) * 72 + st * 16 + lm] = f2bf(p[st]);
    }
}

// ---------------- MFMA flash attention, paired q-tiles (balanced) ----------------
// Grid (NH, 16). Block y handles q-tile A = 64*y (light) and B = 64*(31-y) (heavy):
// constant 33 compute-units/block. 4 waves; wave w owns rows +16w of BOTH tiles,
// sharing every K/V LDS fragment read across the two tiles' MFMAs.
__global__ __launch_bounds__(256) void mla_attn_kernel(
    const ushort_t* __restrict__ qb, const ushort_t* __restrict__ kvb,
    const ushort_t* __restrict__ kpe, const ushort_t* __restrict__ v16t,
    ushort_t* __restrict__ aout16)
{
    __shared__ ushort_t Kn[4 * 64 * 32];    // 16 KB
    __shared__ ushort_t Kr[2 * 64 * 32];    //  8 KB
    __shared__ ushort_t Vt[2 * 128 * 32];   // 16 KB
    __shared__ ushort_t Ps[4][2][16][72];   // 18 KB  [wave][tile][row][64+pad]

    const int h = blockIdx.x;
    const int y = blockIdx.y;               // 0..15
    const int q0A = 64 * y;
    const int q0B = 64 * (31 - y);
    const int tid = threadIdx.x;
    const int w = tid >> 6;
    const int lane = tid & 63;
    const int lm = lane & 15, quad = lane >> 4;
    const int qwA = q0A + 16 * w, qwB = q0B + 16 * w;

    short8 qfA[6], qfB[6];
    #pragma unroll
    for (int f = 0; f < 6; ++f) {
        qfA[f] = *(const short8*)(qb + (size_t)(qwA + lm) * 3072 + h * 192 + f * 32 + quad * 8);
        qfB[f] = *(const short8*)(qb + (size_t)(qwB + lm) * 3072 + h * 192 + f * 32 + quad * 8);
    }

    f32x4 OA[8], OB[8];
    #pragma unroll
    for (int c = 0; c < 8; ++c) {
        OA[c] = (f32x4){0.f, 0.f, 0.f, 0.f};
        OB[c] = (f32x4){0.f, 0.f, 0.f, 0.f};
    }
    float mA[4] = {-1e30f, -1e30f, -1e30f, -1e30f};
    float lA[4] = {0.f, 0.f, 0.f, 0.f};
    float mB[4] = {-1e30f, -1e30f, -1e30f, -1e30f};
    float lB[4] = {0.f, 0.f, 0.f, 0.f};

    const int skey = lane >> 2;
    const int ssub = (lane & 3) * 8;

    const int kend = q0B + 64;
    for (int k0 = 0; k0 < kend; k0 += 64) {
        __syncthreads();
        {
            #pragma unroll
            for (int i = 0; i < 4; ++i)
                gload_lds16(kvb + (size_t)(k0 + i * 16 + skey) * 4096 + h * 256 + w * 32 + ssub,
                            Kn + w * 2048 + i * 512 + lane * 8);
            #pragma unroll
            for (int i = 0; i < 2; ++i) {
                int ii = (w & 1) * 2 + i;
                gload_lds16(kpe + (size_t)(k0 + ii * 16 + skey) * 64 + (w >> 1) * 32 + ssub,
                            Kr + (w >> 1) * 2048 + ii * 512 + lane * 8);
            }
            #pragma unroll
            for (int j = 0; j < 4; ++j) {
                int jj = (w & 1) * 4 + j;
                gload_lds16(v16t + ((size_t)h * 128 + jj * 16 + skey) * S_LEN + k0 + (w >> 1) * 32 + ssub,
                            Vt + (w >> 1) * 4096 + jj * 512 + lane * 8);
            }
        }
        __syncthreads();

        const bool actA = (k0 < qwA + 16);  // wave-uniform; B always active

        // ---- QK^T, kf shared across both tiles ----
        f32x4 sA[4], sB[4];
        #pragma unroll
        for (int st = 0; st < 4; ++st) {
            sA[st] = (f32x4){0.f, 0.f, 0.f, 0.f};
            sB[st] = (f32x4){0.f, 0.f, 0.f, 0.f};
        }
        #pragma unroll
        for (int f = 0; f < 4; ++f)
            #pragma unroll
            for (int st = 0; st < 4; ++st) {
                short8 kf = *(const short8*)(Kn + f * 2048 + (st * 16 + lm) * 32 + quad * 8);
                sA[st] = __builtin_amdgcn_mfma_f32_16x16x32_bf16(qfA[f], kf, sA[st], 0, 0, 0);
                sB[st] = __builtin_amdgcn_mfma_f32_16x16x32_bf16(qfB[f], kf, sB[st], 0, 0, 0);
            }
        #pragma unroll
        for (int f2 = 0; f2 < 2; ++f2)
            #pragma unroll
            for (int st = 0; st < 4; ++st) {
                short8 kf = *(const short8*)(Kr + f2 * 2048 + (st * 16 + lm) * 32 + quad * 8);
                sA[st] = __builtin_amdgcn_mfma_f32_16x16x32_bf16(qfA[4 + f2], kf, sA[st], 0, 0, 0);
                sB[st] = __builtin_amdgcn_mfma_f32_16x16x32_bf16(qfB[4 + f2], kf, sB[st], 0, 0, 0);
            }

        softmax_step(sB, k0, qwB, lm, quad, mB, lB, OB, &Ps[w][1][0][0]);
        if (actA)
            softmax_step(sA, k0, qwA, lm, quad, mA, lA, OA, &Ps[w][0][0][0]);

        asm volatile("s_waitcnt lgkmcnt(0)" ::: "memory");
        short8 pB0 = *(const short8*)(&Ps[w][1][0][0] + lm * 72 + quad * 8);
        short8 pB1 = *(const short8*)(&Ps[w][1][0][0] + lm * 72 + 32 + quad * 8);
        short8 pA0, pA1;
        if (actA) {
            pA0 = *(const short8*)(&Ps[w][0][0][0] + lm * 72 + quad * 8);
            pA1 = *(const short8*)(&Ps[w][0][0][0] + lm * 72 + 32 + quad * 8);
        }
        // ---- PV, vf shared across both tiles ----
        #pragma unroll
        for (int c = 0; c < 8; ++c) {
            short8 vf0 = *(const short8*)(Vt + (c * 16 + lm) * 32 + quad * 8);
            short8 vf1 = *(const short8*)(Vt + 4096 + (c * 16 + lm) * 32 + quad * 8);
            OB[c] = __builtin_amdgcn_mfma_f32_16x16x32_bf16(pB0, vf0, OB[c], 0, 0, 0);
            OB[c] = __builtin_amdgcn_mfma_f32_16x16x32_bf16(pB1, vf1, OB[c], 0, 0, 0);
            if (actA) {
                OA[c] = __builtin_amdgcn_mfma_f32_16x16x32_bf16(pA0, vf0, OA[c], 0, 0, 0);
                OA[c] = __builtin_amdgcn_mfma_f32_16x16x32_bf16(pA1, vf1, OA[c], 0, 0, 0);
            }
        }
    }
    // epilogue
    #pragma unroll
    for (int c = 0; c < 8; ++c)
        #pragma unroll
        for (int r = 0; r < 4; ++r) {
            int rowA = qwA + quad * 4 + r;
            int rowB = qwB + quad * 4 + r;
            aout16[(size_t)rowA * 2048 + h * D_V + c * 16 + lm] = f2bf(OA[c][r] / lA[r]);
            aout16[(size_t)rowB * 2048 + h * D_V + c * 16 + lm] = f2bf(OB[c][r] / lB[r]);
        }
}

extern "C" void kernel_launch(void* const* d_in, const int* in_sizes, int n_in,
                              void* d_out, int out_size, void* d_ws, size_t ws_size,
                              hipStream_t stream)
{
    (void)in_sizes; (void)n_in; (void)out_size; (void)ws_size;
    const float* hs   = (const float*)d_in[0];
    const float* Wqa  = (const float*)d_in[1];
    const float* qlnw = (const float*)d_in[2];
    const float* Wqb  = (const float*)d_in[3];
    const float* Wkva = (const float*)d_in[4];
    const float* klnw = (const float*)d_in[5];
    const float* Wkvb = (const float*)d_in[6];
    const float* Wo   = (const float*)d_in[7];
    float* out = (float*)d_out;

    ushort_t* p = (ushort_t*)d_ws;
    ushort_t* hs16   = p; p += (size_t)S_LEN * H_DIM;
    ushort_t* WcatT  = p; p += (size_t)2176 * H_DIM;     // [Wqa^T 1536 ; Wkva^T 640] x 2048
    ushort_t* WqbT   = p; p += (size_t)3072 * Q_LORA;
    ushort_t* WkvbT  = p; p += (size_t)4096 * KV_LORA;
    ushort_t* WoT    = p; p += (size_t)H_DIM * H_DIM;
    ushort_t* cat16r = p; p += (size_t)S_LEN * 2176;     // [qa_raw 1536 | ckv_raw 512 | kpe_raw 64 | pad]
    ushort_t* qa16   = p; p += (size_t)S_LEN * Q_LORA;
    ushort_t* qbuf16 = p; p += (size_t)S_LEN * 3072;
    ushort_t* ckv16n = p; p += (size_t)S_LEN * KV_LORA;
    ushort_t* kpe16  = p; p += (size_t)S_LEN * D_ROPE;
    ushort_t* kv16   = p; p += (size_t)S_LEN * 4096;
    ushort_t* v16t   = p; p += (size_t)NH * D_V * S_LEN;
    ushort_t* aout16 = p; p += (size_t)S_LEN * 2048;

    // 0. conversions
    conv_f32_bf16<<<(S_LEN * H_DIM / 4 + 255) / 256, 256, 0, stream>>>(hs, hs16, S_LEN * H_DIM);
    convT_kernel<<<dim3(Q_LORA / 32, H_DIM / 32), 256, 0, stream>>>(Wqa, WcatT, H_DIM, Q_LORA);
    convT_kernel<<<dim3(640 / 32, H_DIM / 32), 256, 0, stream>>>(
        Wkva, WcatT + (size_t)Q_LORA * H_DIM, H_DIM, 576);
    convT_kernel<<<dim3(3072 / 32, Q_LORA / 32), 256, 0, stream>>>(Wqb, WqbT, Q_LORA, 3072);
    convT_kernel<<<dim3(4096 / 32, KV_LORA / 32), 256, 0, stream>>>(Wkvb, WkvbT, KV_LORA, 4096);
    convT_kernel<<<dim3(H_DIM / 32, H_DIM / 32), 256, 0, stream>>>(Wo, WoT, H_DIM, H_DIM);

    // 1. cat16r = hs16 @ WcatT^T  [2048 x 2176, K=2048]  (fused Wqa + Wkva)
    mfma_gemm_bt<ushort_t><<<dim3(2176 / 128, S_LEN / 128), 256, 0, stream>>>(
        hs16, WcatT, cat16r, 2176, H_DIM);
    // 2. rmsnorm q (cols 0..1536 of cat16r, stride 2176 -> packed 1536)
    rmsnorm_bf16_kernel<<<S_LEN, 256, 0, stream>>>(cat16r, 2176, qa16, Q_LORA, Q_LORA, qlnw);
    // 3. qbuf16 = qa16 @ WqbT^T  [2048 x 3072, K=1536]
    mfma_gemm_bt<ushort_t><<<dim3(3072 / 128, S_LEN / 128), 256, 0, stream>>>(
        qa16, WqbT, qbuf16, 3072, Q_LORA);
    // 4. rmsnorm kv (cols 1536..2048 of cat16r -> packed 512)
    rmsnorm_bf16_kernel<<<S_LEN, 256, 0, stream>>>(
        cat16r + Q_LORA, 2176, ckv16n, KV_LORA, KV_LORA, klnw);
    // 5. RoPE: q (in place on qbuf16) and k (cat16r cols 2048..2112 -> kpe16)
    rope_bf16_kernel<<<(S_LEN * NH * 32 + 255) / 256, 256, 0, stream>>>(
        qbuf16, 3072, D_NOPE, qbuf16, 3072, D_NOPE, D_QK, NH);
    rope_bf16_kernel<<<(S_LEN * 32 + 255) / 256, 256, 0, stream>>>(
        cat16r, 2176, Q_LORA + KV_LORA, kpe16, D_ROPE, 0, 0, 1);
    // 6. kv16 = ckv16n @ WkvbT^T [2048 x 4096, K=512]
    mfma_gemm_bt<ushort_t><<<dim3(4096 / 128, S_LEN / 128), 256, 0, stream>>>(
        ckv16n, WkvbT, kv16, 4096, KV_LORA);
    // 7. V transpose
    conv_vT_kernel<<<dim3(S_LEN / 32, D_V / 32, NH), 256, 0, stream>>>(kv16, v16t);
    // 8. attention (paired q-tiles, balanced)
    mla_attn_kernel<<<dim3(NH, 16), 256, 0, stream>>>(qbuf16, kv16, kpe16, v16t, aout16);
    // 9. out = aout16 @ WoT^T [2048 x 2048, K=2048], fp32 store
    mfma_gemm_bt<float><<<dim3(H_DIM / 128, S_LEN / 128), 256, 0, stream>>>(
        aout16, WoT, out, H_DIM, H_DIM);
}

// Round 8
// 408.948 us; speedup vs baseline: 8.2499x; 1.0265x over previous
//
#include <hip/hip_runtime.h>
#include <hip/hip_bf16.h>
#include <math.h>

#define S_LEN 2048
#define H_DIM 2048
#define NH 16
#define Q_LORA 1536
#define KV_LORA 512
#define D_NOPE 128
#define D_ROPE 64
#define D_V 128
#define D_QK 192

typedef unsigned short ushort_t;
typedef __attribute__((ext_vector_type(8))) short short8;
typedef __attribute__((ext_vector_type(4))) float f32x4;

__device__ __forceinline__ ushort_t f2bf(float f) {
    unsigned int u = __float_as_uint(f);
    u = (u + 0x7FFFu + ((u >> 16) & 1u)) >> 16;
    return (ushort_t)u;
}
__device__ __forceinline__ float bf2f(ushort_t u) {
    return __uint_as_float(((unsigned int)u) << 16);
}

__device__ __forceinline__ void storeC(float* p, float v) { *p = v; }
__device__ __forceinline__ void storeC(ushort_t* p, float v) { *p = f2bf(v); }

__device__ __forceinline__ void gload_lds16(const ushort_t* g, ushort_t* l) {
    __builtin_amdgcn_global_load_lds(
        (const __attribute__((address_space(1))) unsigned int*)(const void*)g,
        (__attribute__((address_space(3))) unsigned int*)(void*)l, 16, 0, 0);
}

// ---------------- fp32 -> bf16 elementwise (n % 4 == 0) ----------------
__global__ __launch_bounds__(256) void conv_f32_bf16(
    const float* __restrict__ X, ushort_t* __restrict__ Y, int n)
{
    int base = (blockIdx.x * 256 + threadIdx.x) * 4;
    if (base >= n) return;
    float4 v = *(const float4*)(X + base);
    Y[base + 0] = f2bf(v.x);
    Y[base + 1] = f2bf(v.y);
    Y[base + 2] = f2bf(v.z);
    Y[base + 3] = f2bf(v.w);
}

// ------------- weight transpose+convert: W[K][N] f32 -> Wt[Npad][K] bf16 -------------
__global__ __launch_bounds__(256) void convT_kernel(
    const float* __restrict__ W, ushort_t* __restrict__ Wt, int K, int N)
{
    __shared__ float tile[32][33];
    const int k0 = blockIdx.y * 32, n0 = blockIdx.x * 32;
    const int tr = threadIdx.x >> 5, tc = threadIdx.x & 31;
    #pragma unroll
    for (int i = 0; i < 4; ++i) {
        int r = tr + i * 8;
        float v = 0.f;
        if (n0 + tc < N) v = W[(size_t)(k0 + r) * N + n0 + tc];
        tile[r][tc] = v;
    }
    __syncthreads();
    #pragma unroll
    for (int i = 0; i < 4; ++i) {
        int r = tr + i * 8;  // n-index within tile
        Wt[(size_t)(n0 + r) * K + k0 + tc] = f2bf(tile[tc][r]);
    }
}

// ---------------- bf16 rmsnorm ----------------
__global__ __launch_bounds__(256) void rmsnorm_bf16_kernel(
    const ushort_t* __restrict__ X, int inStride,
    ushort_t* __restrict__ Y, int outStride, int K, const float* __restrict__ w)
{
    __shared__ float red[4];
    const ushort_t* x = X + (size_t)blockIdx.x * inStride;
    ushort_t* y = Y + (size_t)blockIdx.x * outStride;
    float ss = 0.f;
    for (int i = threadIdx.x; i < K; i += 256) { float v = bf2f(x[i]); ss += v * v; }
    #pragma unroll
    for (int off = 32; off > 0; off >>= 1) ss += __shfl_down(ss, off);
    int lane = threadIdx.x & 63, wid = threadIdx.x >> 6;
    if (lane == 0) red[wid] = ss;
    __syncthreads();
    float tot = red[0] + red[1] + red[2] + red[3];
    float rs = rsqrtf(tot / (float)K + 1e-6f);
    for (int i = threadIdx.x; i < K; i += 256)
        y[i] = f2bf(bf2f(x[i]) * rs * w[i]);
}

// ---------------- bf16 RoPE ----------------
__global__ void rope_bf16_kernel(
    const ushort_t* __restrict__ src, int srcStride, int srcOff,
    ushort_t* __restrict__ dst, int dstStride, int dstOff,
    int headStride, int nHeads)
{
    int idx = blockIdx.x * 256 + threadIdx.x;
    if (idx >= S_LEN * nHeads * 32) return;
    int i = idx & 31;
    int sh = idx >> 5;
    int hh = sh % nHeads;
    int s = sh / nHeads;
    float inv = powf(10000.0f, -(2.0f * i) / 64.0f);
    float ang = (float)s * inv;
    float c = cosf(ang), sn = sinf(ang);
    const ushort_t* p = src + (size_t)s * srcStride + hh * headStride + srcOff;
    ushort_t* q = dst + (size_t)s * dstStride + hh * headStride + dstOff;
    float x1 = bf2f(p[i]), x2 = bf2f(p[i + 32]);
    q[i]      = f2bf(x1 * c - x2 * sn);
    q[i + 32] = f2bf(x2 * c + x1 * sn);
}

// ---------------- V transpose: kv16[s][h*256+128+dv] -> v16t[h][dv][s] ----------------
__global__ __launch_bounds__(256) void conv_vT_kernel(
    const ushort_t* __restrict__ kv, ushort_t* __restrict__ v16t)
{
    __shared__ ushort_t tile[32][33];
    const int h = blockIdx.z;
    const int s0 = blockIdx.x * 32, d0 = blockIdx.y * 32;
    const int tr = threadIdx.x >> 5, tc = threadIdx.x & 31;
    #pragma unroll
    for (int i = 0; i < 4; ++i) {
        int r = tr + i * 8;  // s
        tile[r][tc] = kv[(size_t)(s0 + r) * 4096 + h * 256 + D_NOPE + d0 + tc];
    }
    __syncthreads();
    #pragma unroll
    for (int i = 0; i < 4; ++i) {
        int r = tr + i * 8;  // dv
        v16t[(size_t)h * D_V * S_LEN + (size_t)(d0 + r) * S_LEN + s0 + tc] = tile[tc][r];
    }
}

// ---------------- m97-style MFMA GEMM: C[M][N] = A[M][K] * Bt[N][K]^T ----------------
template <typename CT>
__global__ __launch_bounds__(256) void mfma_gemm_bt(
    const ushort_t* __restrict__ A, const ushort_t* __restrict__ Bt,
    CT* __restrict__ C, int N, int K)
{
    __shared__ ushort_t Al[128 * 32];
    __shared__ ushort_t Bl[128 * 32];
    const int m0 = blockIdx.y * 128, n0 = blockIdx.x * 128;
    const int tid = threadIdx.x;
    const int lane = tid & 63;
    const int w = tid >> 6;
    const int lm = lane & 15, quad = lane >> 4;
    const int wr = w >> 1, wc = w & 1;

    f32x4 acc[4][4];
    #pragma unroll
    for (int a = 0; a < 4; ++a)
        #pragma unroll
        for (int b = 0; b < 4; ++b) acc[a][b] = (f32x4){0.f, 0.f, 0.f, 0.f};

    const int rrow = tid >> 2;
    const int rcol = (tid & 3) * 8;

    for (int k0 = 0; k0 < K; k0 += 32) {
        __syncthreads();
        #pragma unroll
        for (int i = 0; i < 2; ++i) {
            int row = i * 64 + rrow;
            gload_lds16(A  + (size_t)(m0 + row) * K + k0 + rcol, Al + (i * 256 + tid) * 8);
            gload_lds16(Bt + (size_t)(n0 + row) * K + k0 + rcol, Bl + (i * 256 + tid) * 8);
        }
        __syncthreads();

        short8 af[4], bf[4];
        #pragma unroll
        for (int t = 0; t < 4; ++t) {
            af[t] = *(const short8*)(Al + (wr * 64 + t * 16 + lm) * 32 + quad * 8);
            bf[t] = *(const short8*)(Bl + (wc * 64 + t * 16 + lm) * 32 + quad * 8);
        }
        #pragma unroll
        for (int mt = 0; mt < 4; ++mt)
            #pragma unroll
            for (int nt = 0; nt < 4; ++nt)
                acc[mt][nt] = __builtin_amdgcn_mfma_f32_16x16x32_bf16(
                    af[mt], bf[nt], acc[mt][nt], 0, 0, 0);
    }

    #pragma unroll
    for (int mt = 0; mt < 4; ++mt)
        #pragma unroll
        for (int nt = 0; nt < 4; ++nt)
            #pragma unroll
            for (int r = 0; r < 4; ++r) {
                int row = m0 + wr * 64 + mt * 16 + quad * 4 + r;
                int col = n0 + wc * 64 + nt * 16 + lm;
                storeC(&C[(size_t)row * N + col], acc[mt][nt][r]);
            }
}

// online-softmax update for one 16x64 score tile in C layout; writes P (bf16) to ps[16][72]
__device__ __forceinline__ void softmax_step(
    f32x4 s[4], int k0, int qw, int lm, int quad,
    float m_[4], float l_[4], f32x4 O[8], ushort_t* ps)
{
    const float scale = 0.07216878364870322f;  // 192^-0.5
    #pragma unroll
    for (int r = 0; r < 4; ++r) {
        int qrow = qw + quad * 4 + r;
        float a[4];
        #pragma unroll
        for (int st = 0; st < 4; ++st)
            a[st] = (k0 + st * 16 + lm <= qrow) ? s[st][r] * scale : -1e30f;
        float mx = fmaxf(fmaxf(a[0], a[1]), fmaxf(a[2], a[3]));
        mx = fmaxf(mx, __shfl_xor(mx, 1));
        mx = fmaxf(mx, __shfl_xor(mx, 2));
        mx = fmaxf(mx, __shfl_xor(mx, 4));
        mx = fmaxf(mx, __shfl_xor(mx, 8));
        float mn = fmaxf(m_[r], mx);
        float p[4];
        #pragma unroll
        for (int st = 0; st < 4; ++st) p[st] = __expf(a[st] - mn);
        float alpha = __expf(m_[r] - mn);
        float psum = (p[0] + p[1]) + (p[2] + p[3]);
        psum += __shfl_xor(psum, 1);
        psum += __shfl_xor(psum, 2);
        psum += __shfl_xor(psum, 4);
        psum += __shfl_xor(psum, 8);
        l_[r] = l_[r] * alpha + psum;
        m_[r] = mn;
        #pragma unroll
        for (int c = 0; c < 8; ++c) O[c][r] *= alpha;
        #pragma unroll
        for (int st = 0; st < 4; ++st)
            ps[(quad * 4 + r) * 72 + st * 16 + lm] = f2bf(p[st]);
    }
}

// ---------------- MFMA flash attention: 32-row q-tiles, 2-wave blocks ----------------
// Grid (NH, 64), heavy-first (q0 = 32*(63-by)). 128 threads = 2 waves; wave w owns
// rows [q0+16w, q0+16w+16). Per 64-key round both waves cooperatively stage
// K-nope/K-rope/V^T into LDS (global_load_lds, 20 instr/wave), then each wave does
// QK^T -> online softmax -> PV. LDS 44.5 KB -> 3 blocks/CU; 1024 blocks over
// ~768 slots gives backfill balancing of the causal triangle.
__global__ __launch_bounds__(128) void mla_attn_kernel(
    const ushort_t* __restrict__ qb, const ushort_t* __restrict__ kvb,
    const ushort_t* __restrict__ kpe, const ushort_t* __restrict__ v16t,
    ushort_t* __restrict__ aout16)
{
    __shared__ ushort_t Kn[4 * 64 * 32];   // 16 KB [f 0..3][key 0..63][32]
    __shared__ ushort_t Kr[2 * 64 * 32];   //  8 KB [f2 0..1][key][32]
    __shared__ ushort_t Vt[2 * 128 * 32];  // 16 KB [half 0..1][dv 0..127][32]
    __shared__ ushort_t Ps[2][16][72];     // 4.5 KB per-wave P

    const int h = blockIdx.x;
    const int q0 = 32 * (63 - blockIdx.y);  // heavy-first
    const int w = threadIdx.x >> 6;         // 0..1
    const int lane = threadIdx.x & 63;
    const int lm = lane & 15, quad = lane >> 4;
    const int qw = q0 + 16 * w;
    ushort_t* myPs = &Ps[w][0][0];

    short8 qf[6];
    #pragma unroll
    for (int f = 0; f < 6; ++f)
        qf[f] = *(const short8*)(qb + (size_t)(qw + lm) * 3072 + h * 192 + f * 32 + quad * 8);

    f32x4 O[8];
    #pragma unroll
    for (int c = 0; c < 8; ++c) O[c] = (f32x4){0.f, 0.f, 0.f, 0.f};
    float m_[4] = {-1e30f, -1e30f, -1e30f, -1e30f};
    float l_[4] = {0.f, 0.f, 0.f, 0.f};

    const int skey = lane >> 2;        // 0..15
    const int ssub = (lane & 3) * 8;   // 0/8/16/24

    const int kend = q0 + 32;
    for (int k0 = 0; k0 < kend; k0 += 64) {
        __syncthreads();
        {
            // K-nope: wave w covers f in {2w, 2w+1}, i = 0..3 (8 instr/wave)
            #pragma unroll
            for (int fi = 0; fi < 2; ++fi) {
                int f = 2 * w + fi;
                #pragma unroll
                for (int i = 0; i < 4; ++i)
                    gload_lds16(kvb + (size_t)(k0 + i * 16 + skey) * 4096 + h * 256 + f * 32 + ssub,
                                Kn + f * 2048 + i * 512 + lane * 8);
            }
            // K-rope: f2 = w, i = 0..3 (4 instr/wave)
            #pragma unroll
            for (int i = 0; i < 4; ++i)
                gload_lds16(kpe + (size_t)(k0 + i * 16 + skey) * 64 + w * 32 + ssub,
                            Kr + w * 2048 + i * 512 + lane * 8);
            // V^T: half = w, j = 0..7 (8 instr/wave)
            #pragma unroll
            for (int j = 0; j < 8; ++j)
                gload_lds16(v16t + ((size_t)h * 128 + j * 16 + skey) * S_LEN + k0 + w * 32 + ssub,
                            Vt + w * 4096 + j * 512 + lane * 8);
        }
        __syncthreads();

        if (k0 < qw + 16) {  // wave-uniform causal skip (wave 1 always active)
            f32x4 s[4];
            #pragma unroll
            for (int st = 0; st < 4; ++st) s[st] = (f32x4){0.f, 0.f, 0.f, 0.f};
            #pragma unroll
            for (int f = 0; f < 4; ++f)
                #pragma unroll
                for (int st = 0; st < 4; ++st) {
                    short8 kf = *(const short8*)(Kn + f * 2048 + (st * 16 + lm) * 32 + quad * 8);
                    s[st] = __builtin_amdgcn_mfma_f32_16x16x32_bf16(qf[f], kf, s[st], 0, 0, 0);
                }
            #pragma unroll
            for (int f2 = 0; f2 < 2; ++f2)
                #pragma unroll
                for (int st = 0; st < 4; ++st) {
                    short8 kf = *(const short8*)(Kr + f2 * 2048 + (st * 16 + lm) * 32 + quad * 8);
                    s[st] = __builtin_amdgcn_mfma_f32_16x16x32_bf16(qf[4 + f2], kf, s[st], 0, 0, 0);
                }

            softmax_step(s, k0, qw, lm, quad, m_, l_, O, myPs);

            asm volatile("s_waitcnt lgkmcnt(0)" ::: "memory");
            short8 pf0 = *(const short8*)(myPs + lm * 72 + quad * 8);
            short8 pf1 = *(const short8*)(myPs + lm * 72 + 32 + quad * 8);
            #pragma unroll
            for (int c = 0; c < 8; ++c) {
                short8 vf0 = *(const short8*)(Vt + (c * 16 + lm) * 32 + quad * 8);
                short8 vf1 = *(const short8*)(Vt + 4096 + (c * 16 + lm) * 32 + quad * 8);
                O[c] = __builtin_amdgcn_mfma_f32_16x16x32_bf16(pf0, vf0, O[c], 0, 0, 0);
                O[c] = __builtin_amdgcn_mfma_f32_16x16x32_bf16(pf1, vf1, O[c], 0, 0, 0);
            }
        }
    }
    // epilogue
    #pragma unroll
    for (int c = 0; c < 8; ++c)
        #pragma unroll
        for (int r = 0; r < 4; ++r) {
            int qrow = qw + quad * 4 + r;
            aout16[(size_t)qrow * 2048 + h * D_V + c * 16 + lm] = f2bf(O[c][r] / l_[r]);
        }
}

extern "C" void kernel_launch(void* const* d_in, const int* in_sizes, int n_in,
                              void* d_out, int out_size, void* d_ws, size_t ws_size,
                              hipStream_t stream)
{
    (void)in_sizes; (void)n_in; (void)out_size; (void)ws_size;
    const float* hs   = (const float*)d_in[0];
    const float* Wqa  = (const float*)d_in[1];
    const float* qlnw = (const float*)d_in[2];
    const float* Wqb  = (const float*)d_in[3];
    const float* Wkva = (const float*)d_in[4];
    const float* klnw = (const float*)d_in[5];
    const float* Wkvb = (const float*)d_in[6];
    const float* Wo   = (const float*)d_in[7];
    float* out = (float*)d_out;

    ushort_t* p = (ushort_t*)d_ws;
    ushort_t* hs16   = p; p += (size_t)S_LEN * H_DIM;
    ushort_t* WcatT  = p; p += (size_t)2176 * H_DIM;     // [Wqa^T 1536 ; Wkva^T 640] x 2048
    ushort_t* WqbT   = p; p += (size_t)3072 * Q_LORA;
    ushort_t* WkvbT  = p; p += (size_t)4096 * KV_LORA;
    ushort_t* WoT    = p; p += (size_t)H_DIM * H_DIM;
    ushort_t* cat16r = p; p += (size_t)S_LEN * 2176;     // [qa_raw 1536 | ckv_raw 512 | kpe_raw 64 | pad]
    ushort_t* qa16   = p; p += (size_t)S_LEN * Q_LORA;
    ushort_t* qbuf16 = p; p += (size_t)S_LEN * 3072;
    ushort_t* ckv16n = p; p += (size_t)S_LEN * KV_LORA;
    ushort_t* kpe16  = p; p += (size_t)S_LEN * D_ROPE;
    ushort_t* kv16   = p; p += (size_t)S_LEN * 4096;
    ushort_t* v16t   = p; p += (size_t)NH * D_V * S_LEN;
    ushort_t* aout16 = p; p += (size_t)S_LEN * 2048;

    // 0. conversions
    conv_f32_bf16<<<(S_LEN * H_DIM / 4 + 255) / 256, 256, 0, stream>>>(hs, hs16, S_LEN * H_DIM);
    convT_kernel<<<dim3(Q_LORA / 32, H_DIM / 32), 256, 0, stream>>>(Wqa, WcatT, H_DIM, Q_LORA);
    convT_kernel<<<dim3(640 / 32, H_DIM / 32), 256, 0, stream>>>(
        Wkva, WcatT + (size_t)Q_LORA * H_DIM, H_DIM, 576);
    convT_kernel<<<dim3(3072 / 32, Q_LORA / 32), 256, 0, stream>>>(Wqb, WqbT, Q_LORA, 3072);
    convT_kernel<<<dim3(4096 / 32, KV_LORA / 32), 256, 0, stream>>>(Wkvb, WkvbT, KV_LORA, 4096);
    convT_kernel<<<dim3(H_DIM / 32, H_DIM / 32), 256, 0, stream>>>(Wo, WoT, H_DIM, H_DIM);

    // 1. cat16r = hs16 @ WcatT^T  [2048 x 2176, K=2048]  (fused Wqa + Wkva)
    mfma_gemm_bt<ushort_t><<<dim3(2176 / 128, S_LEN / 128), 256, 0, stream>>>(
        hs16, WcatT, cat16r, 2176, H_DIM);
    // 2. rmsnorm q (cols 0..1536 of cat16r, stride 2176 -> packed 1536)
    rmsnorm_bf16_kernel<<<S_LEN, 256, 0, stream>>>(cat16r, 2176, qa16, Q_LORA, Q_LORA, qlnw);
    // 3. qbuf16 = qa16 @ WqbT^T  [2048 x 3072, K=1536]
    mfma_gemm_bt<ushort_t><<<dim3(3072 / 128, S_LEN / 128), 256, 0, stream>>>(
        qa16, WqbT, qbuf16, 3072, Q_LORA);
    // 4. rmsnorm kv (cols 1536..2048 of cat16r -> packed 512)
    rmsnorm_bf16_kernel<<<S_LEN, 256, 0, stream>>>(
        cat16r + Q_LORA, 2176, ckv16n, KV_LORA, KV_LORA, klnw);
    // 5. RoPE: q (in place on qbuf16) and k (cat16r cols 2048..2112 -> kpe16)
    rope_bf16_kernel<<<(S_LEN * NH * 32 + 255) / 256, 256, 0, stream>>>(
        qbuf16, 3072, D_NOPE, qbuf16, 3072, D_NOPE, D_QK, NH);
    rope_bf16_kernel<<<(S_LEN * 32 + 255) / 256, 256, 0, stream>>>(
        cat16r, 2176, Q_LORA + KV_LORA, kpe16, D_ROPE, 0, 0, 1);
    // 6. kv16 = ckv16n @ WkvbT^T [2048 x 4096, K=512]
    mfma_gemm_bt<ushort_t><<<dim3(4096 / 128, S_LEN / 128), 256, 0, stream>>>(
        ckv16n, WkvbT, kv16, 4096, KV_LORA);
    // 7. V transpose
    conv_vT_kernel<<<dim3(S_LEN / 32, D_V / 32, NH), 256, 0, stream>>>(kv16, v16t);
    // 8. attention (32-row tiles, 2-wave blocks, 3 blocks/CU + backfill)
    mla_attn_kernel<<<dim3(NH, 64), 128, 0, stream>>>(qbuf16, kv16, kpe16, v16t, aout16);
    // 9. out = aout16 @ WoT^T [2048 x 2048, K=2048], fp32 store
    mfma_gemm_bt<float><<<dim3(H_DIM / 128, S_LEN / 128), 256, 0, stream>>>(
        aout16, WoT, out, H_DIM, H_DIM);
}